// Round 12
// baseline (309.410 us; speedup 1.0000x reference)
//
#include <hip/hip_runtime.h>
#include <hip/hip_bf16.h>
#include <math.h>

typedef __bf16 bf16_t;
typedef __bf16 bf16x8 __attribute__((ext_vector_type(8)));
typedef __bf16 bf16x4 __attribute__((ext_vector_type(4)));
typedef float  f32x4  __attribute__((ext_vector_type(4)));
typedef unsigned int u32;

static constexpr int C_    = 1024;
static constexpr int NH    = 16;
static constexpr int DH    = 64;
static constexpr int BB    = 2;
static constexpr int TT    = 2048;
static constexpr int MROWS = BB * TT;   // 4096
static constexpr float LOG2E = 1.4426950408889634f;

// ---------------- helpers ----------------------------------------------------
__device__ __forceinline__ void gload_lds16(const bf16_t* src, bf16_t* dst) {
  __builtin_amdgcn_global_load_lds(
      (const __attribute__((address_space(1))) u32*)(src),
      (__attribute__((address_space(3))) u32*)(dst),
      16, 0, 0);
}

__device__ __forceinline__ u32 cvt_pk_bf16(float a, float b) {
  u32 r;
  asm("v_cvt_pk_bf16_f32 %0, %1, %2" : "=v"(r) : "v"(a), "v"(b));
  return r;
}

__device__ __forceinline__ float fexp2(float x) {
#if __has_builtin(__builtin_amdgcn_exp2f)
  return __builtin_amdgcn_exp2f(x);
#else
  return exp2f(x);
#endif
}
__device__ __forceinline__ float frcp(float x) {
#if __has_builtin(__builtin_amdgcn_rcpf)
  return __builtin_amdgcn_rcpf(x);
#else
  return 1.0f / x;
#endif
}

// cumulative item index for strip-of-16 s and chunk c (pid scheme, P4)
__device__ __forceinline__ int sc_to_t(int s, int c) {
  if (s < 32)  return s;
  if (s < 64)  return 32 + (s - 32) * 2 + c;
  if (s < 96)  return 96 + (s - 64) * 3 + c;
  return 192 + (s - 96) * 4 + c;
}

// block item (128-row group) mapping: item in [0,40) -> (gu in [0,16), c)
__device__ __forceinline__ void item40_to_uc(int t, int& u, int& c) {
  if (t < 4)       { u = t;                c = 0; }
  else if (t < 12) { int v = t - 4;  u = 4  + (v >> 1); c = v & 1; }
  else if (t < 24) { int v = t - 12; u = 8  + v / 3;    c = v - 3 * (v / 3); }
  else             { int v = t - 24; u = 12 + (v >> 2); c = v & 3; }
}

// ---------------- LayerNorm (fp32 in) -> bf16 out ---------------------------
__global__ __launch_bounds__(256) void ln_bf16(
    const float* __restrict__ x, const float* __restrict__ w,
    const float* __restrict__ b, bf16_t* __restrict__ out)
{
  const int row = blockIdx.x;
  const int tid = threadIdx.x;
  const float4 v = reinterpret_cast<const float4*>(x + (size_t)row * C_)[tid];
  float s  = v.x + v.y + v.z + v.w;
  float s2 = v.x*v.x + v.y*v.y + v.z*v.z + v.w*v.w;
#pragma unroll
  for (int m = 1; m < 64; m <<= 1) { s += __shfl_xor(s, m); s2 += __shfl_xor(s2, m); }
  __shared__ float red[8];
  const int wv = tid >> 6;
  if ((tid & 63) == 0) { red[wv] = s; red[4 + wv] = s2; }
  __syncthreads();
  s  = red[0] + red[1] + red[2] + red[3];
  s2 = red[4] + red[5] + red[6] + red[7];
  const float mu   = s * (1.0f / C_);
  const float rstd = rsqrtf(s2 * (1.0f / C_) - mu * mu + 1e-5f);
  const float4 wv4 = reinterpret_cast<const float4*>(w)[tid];
  const float4 bv4 = reinterpret_cast<const float4*>(b)[tid];
  bf16x4 o;
  o[0] = (bf16_t)((v.x - mu) * rstd * wv4.x + bv4.x);
  o[1] = (bf16_t)((v.y - mu) * rstd * wv4.y + bv4.y);
  o[2] = (bf16_t)((v.z - mu) * rstd * wv4.z + bv4.z);
  o[3] = (bf16_t)((v.w - mu) * rstd * wv4.w + bv4.w);
  *reinterpret_cast<bf16x4*>(out + (size_t)row * C_ + tid * 4) = o;
}

// ---------------- LN2 fused with proj split-K combine ------------------------
__global__ __launch_bounds__(256) void ln2_fuse(
    const float* __restrict__ p0, const bf16_t* __restrict__ p1,
    const float* __restrict__ xin, const float* __restrict__ pbias,
    const float* __restrict__ w, const float* __restrict__ b,
    float* __restrict__ x2out, bf16_t* __restrict__ out)
{
  const int row = blockIdx.x;
  const int tid = threadIdx.x;
  const size_t base = (size_t)row * C_ + tid * 4;
  const float4 v0 = *reinterpret_cast<const float4*>(p0 + base);
  const bf16x4 v1 = *reinterpret_cast<const bf16x4*>(p1 + base);
  const float4 xr = *reinterpret_cast<const float4*>(xin + base);
  const float4 pb = *reinterpret_cast<const float4*>(pbias + tid * 4);
  float4 v;
  v.x = v0.x + (float)v1[0] + pb.x + xr.x;
  v.y = v0.y + (float)v1[1] + pb.y + xr.y;
  v.z = v0.z + (float)v1[2] + pb.z + xr.z;
  v.w = v0.w + (float)v1[3] + pb.w + xr.w;
  *reinterpret_cast<float4*>(x2out + base) = v;

  float s  = v.x + v.y + v.z + v.w;
  float s2 = v.x*v.x + v.y*v.y + v.z*v.z + v.w*v.w;
#pragma unroll
  for (int m = 1; m < 64; m <<= 1) { s += __shfl_xor(s, m); s2 += __shfl_xor(s2, m); }
  __shared__ float red[8];
  const int wv = tid >> 6;
  if ((tid & 63) == 0) { red[wv] = s; red[4 + wv] = s2; }
  __syncthreads();
  s  = red[0] + red[1] + red[2] + red[3];
  s2 = red[4] + red[5] + red[6] + red[7];
  const float mu   = s * (1.0f / C_);
  const float rstd = rsqrtf(s2 * (1.0f / C_) - mu * mu + 1e-5f);
  const float4 wv4 = reinterpret_cast<const float4*>(w)[tid];
  const float4 bv4 = reinterpret_cast<const float4*>(b)[tid];
  bf16x4 o;
  o[0] = (bf16_t)((v.x - mu) * rstd * wv4.x + bv4.x);
  o[1] = (bf16_t)((v.y - mu) * rstd * wv4.y + bv4.y);
  o[2] = (bf16_t)((v.z - mu) * rstd * wv4.z + bv4.z);
  o[3] = (bf16_t)((v.w - mu) * rstd * wv4.w + bv4.w);
  *reinterpret_cast<bf16x4*>(out + base) = o;
}

// ---------------- combine for mlp_proj split-K -------------------------------
__global__ __launch_bounds__(256) void combine3(
    float* __restrict__ out, const bf16_t* __restrict__ p1,
    const bf16_t* __restrict__ p2, const bf16_t* __restrict__ p3,
    const float* __restrict__ bias, const float* __restrict__ resid)
{
  const size_t idx = ((size_t)blockIdx.x * 256 + threadIdx.x) * 4;
  float4 o = *reinterpret_cast<const float4*>(out + idx);
  const bf16x4 a = *reinterpret_cast<const bf16x4*>(p1 + idx);
  const bf16x4 b = *reinterpret_cast<const bf16x4*>(p2 + idx);
  const bf16x4 c = *reinterpret_cast<const bf16x4*>(p3 + idx);
  const float4 r = *reinterpret_cast<const float4*>(resid + idx);
  const int col = (int)(idx & (C_ - 1));
  const float4 bv = *reinterpret_cast<const float4*>(bias + col);
  o.x += (float)a[0] + (float)b[0] + (float)c[0] + bv.x + r.x;
  o.y += (float)a[1] + (float)b[1] + (float)c[1] + bv.y + r.y;
  o.z += (float)a[2] + (float)b[2] + (float)c[2] + bv.z + r.z;
  o.w += (float)a[3] + (float)b[3] + (float)c[3] + bv.w + r.w;
  *reinterpret_cast<float4*>(out + idx) = o;
}

// ---------------- weight transpose+convert: fp32 [K][N] -> bf16 [N][K] ------
__global__ __launch_bounds__(256) void transpose_w(
    const float* __restrict__ in, bf16_t* __restrict__ out, int K, int N)
{
  __shared__ float tile[32][33];
  const int tx = threadIdx.x & 31, ty = threadIdx.x >> 5;
  const int n0 = blockIdx.x * 32, k0 = blockIdx.y * 32;
#pragma unroll
  for (int i = 0; i < 4; ++i)
    tile[ty + i * 8][tx] = in[(size_t)(k0 + ty + i * 8) * N + n0 + tx];
  __syncthreads();
#pragma unroll
  for (int i = 0; i < 4; ++i)
    out[(size_t)(n0 + ty + i * 8) * K + k0 + tx] = (bf16_t)tile[tx][ty + i * 8];
}

// ---------------- 256x128 GEMM, 8 waves, 3-buffer LDS, counted vmcnt ---------
// EPI 0: +bias qkv scatter (V written TRANSPOSED -> vT[B,H,D,T])
// EPI 2: +bias gelu bf16
template<int EPI>
__global__ __launch_bounds__(512, 1) void gemmP(
    const bf16_t* __restrict__ A, const bf16_t* __restrict__ Bt,
    const float* __restrict__ bias, float* __restrict__ fout,
    bf16_t* __restrict__ bout0, bf16_t* __restrict__ bout1,
    bf16_t* __restrict__ bout2, int N, int Kc, int Kfull, int nbn)
{
  __shared__ bf16_t As[3][256 * 64];   // 96 KB
  __shared__ bf16_t Bs[3][128 * 64];   // 48 KB
  const int tid  = threadIdx.x;
  const int wave = tid >> 6, lane = tid & 63;
  const int r = lane & 15, g = lane >> 4;
  const int wm = wave >> 2, wn = wave & 3;   // 2 x 4 waves: 128 x 32 per wave

  const int cpx = gridDim.x >> 3;
  const int swz = (blockIdx.x & 7) * cpx + (blockIdx.x >> 3);
  const int bm = swz / nbn, bn = swz - bm * nbn;
  const int z  = blockIdx.z;
  const int k0 = z * Kc;

  const bf16_t* Abase = A  + (size_t)bm * 256 * Kfull + k0;
  const bf16_t* Bbase = Bt + (size_t)bn * 128 * Kfull + k0;

  f32x4 acc[8][2] = {};

  auto STG_A = [&](int buf, int kt, int pass) {
    const int idx = pass * 512 + tid;
    const int rr = idx >> 3, cc = idx & 7, gs = cc ^ (rr & 7);
    gload_lds16(Abase + (size_t)rr * Kfull + kt + gs * 8, &As[buf][idx * 8]);
  };
  auto STG_B = [&](int buf, int kt, int pass) {
    const int idx = pass * 512 + tid;
    const int rr = idx >> 3, cc = idx & 7, gs = cc ^ (rr & 7);
    gload_lds16(Bbase + (size_t)rr * Kfull + kt + gs * 8, &Bs[buf][idx * 8]);
  };
  auto STAGE6 = [&](int buf, int kt) {
    STG_A(buf, kt, 0); STG_A(buf, kt, 1);
    STG_A(buf, kt, 2); STG_A(buf, kt, 3);
    STG_B(buf, kt, 0); STG_B(buf, kt, 1);
  };

  const int NT = Kc >> 6;
  STAGE6(0, 0);
  STAGE6(1, 64);

  for (int t = 0; t < NT; ++t) {
    const int buf = t % 3;
    if (t + 1 < NT) asm volatile("s_waitcnt vmcnt(6)" ::: "memory");
    else            asm volatile("s_waitcnt vmcnt(0)" ::: "memory");
    __builtin_amdgcn_s_barrier();
    asm volatile("" ::: "memory");

    const bool pre = (t + 2 < NT);
    const int kn   = (t + 2) << 6;
    const int bnx  = (t + 2) % 3;

    bf16x8 bfr[2][2];
#pragma unroll
    for (int s2 = 0; s2 < 2; ++s2)
#pragma unroll
      for (int ni = 0; ni < 2; ++ni) {
        const int rr = wn * 32 + ni * 16 + r;
        bfr[s2][ni] = *reinterpret_cast<const bf16x8*>(
            &Bs[buf][rr * 64 + (((s2 << 2) | g) ^ (rr & 7)) * 8]);
      }
#pragma unroll
    for (int mh = 0; mh < 2; ++mh) {
      bf16x8 af[2][4];
#pragma unroll
      for (int s2 = 0; s2 < 2; ++s2)
#pragma unroll
        for (int mi = 0; mi < 4; ++mi) {
          const int rr = wm * 128 + (mh * 4 + mi) * 16 + r;
          af[s2][mi] = *reinterpret_cast<const bf16x8*>(
              &As[buf][rr * 64 + (((s2 << 2) | g) ^ (rr & 7)) * 8]);
        }
      if (pre) {
        if (mh == 0) { STG_A(bnx, kn, 0); STG_A(bnx, kn, 1); STG_A(bnx, kn, 2); }
        else         { STG_A(bnx, kn, 3); STG_B(bnx, kn, 0); STG_B(bnx, kn, 1); }
      }
      __builtin_amdgcn_s_setprio(1);
#pragma unroll
      for (int s2 = 0; s2 < 2; ++s2)
#pragma unroll
        for (int mi = 0; mi < 4; ++mi)
#pragma unroll
          for (int ni = 0; ni < 2; ++ni)
            acc[mh * 4 + mi][ni] = __builtin_amdgcn_mfma_f32_16x16x32_bf16(
                af[s2][mi], bfr[s2][ni], acc[mh * 4 + mi][ni], 0, 0, 0);
      __builtin_amdgcn_s_setprio(0);
    }
  }

#pragma unroll
  for (int mi = 0; mi < 8; ++mi) {
#pragma unroll
    for (int ni = 0; ni < 2; ++ni) {
      const int grow0 = bm * 256 + wm * 128 + mi * 16 + g * 4;
      const int gcol  = bn * 128 + wn * 32 + ni * 16 + r;
      const float bv = bias[gcol];
#pragma unroll
      for (int i = 0; i < 4; ++i) {
        const int grow = grow0 + i;
        const float v = acc[mi][ni][i] + bv;
        if constexpr (EPI == 0) {
          const int which = gcol >> 10;
          const int c0 = gcol & 1023;
          const int hh = c0 >> 6, dd = c0 & 63;
          const int bb = grow >> 11, tt = grow & 2047;
          if (which == 2)   // V transposed: [B,H,D,T]
            bout2[((size_t)(bb * NH + hh) * DH + dd) * TT + tt] = (bf16_t)v;
          else {
            bf16_t* dst = (which == 0) ? bout0 : bout1;
            dst[((size_t)(bb * NH + hh) * TT + tt) * DH + dd] = (bf16_t)v;
          }
        } else {
          const float gl = 0.5f * v * (1.0f + erff(v * 0.70710678118654752f));
          bout0[(size_t)grow * N + gcol] = (bf16_t)gl;
        }
      }
    }
  }
}

// ---------------- 128x128 GEMM (split-K raw partial epilogue) ---------------
__global__ __launch_bounds__(256) void gemm_sk(
    const bf16_t* __restrict__ A, const bf16_t* __restrict__ Bt,
    float* __restrict__ fout, bf16_t* __restrict__ bout0,
    bf16_t* __restrict__ bout1, bf16_t* __restrict__ bout2,
    int M, int N, int Kc, int Kfull)
{
  constexpr int BM = 128, BN = 128, BK = 64;
  __shared__ bf16_t As[BM * BK];
  __shared__ bf16_t Bs[BN * BK];
  const int tid  = threadIdx.x;
  const int wave = tid >> 6, lane = tid & 63;
  const int r = lane & 15, g = lane >> 4;
  const int wm = wave >> 1, wn = wave & 1;
  const int bm = blockIdx.x, bn = blockIdx.y;
  const int z  = blockIdx.z;
  const int kstart = z * Kc;

  const bf16_t* Abase = A  + (size_t)bm * BM * Kfull;
  const bf16_t* Bbase = Bt + (size_t)bn * BN * Kfull;

  f32x4 acc[4][4] = {};

  for (int kt = kstart; kt < kstart + Kc; kt += BK) {
#pragma unroll
    for (int it = 0; it < 4; ++it) {
      const int c0 = it * 256 + wave * 64;
      const int idx = c0 + lane;
      const int rr = idx >> 3, cc = idx & 7;
      const int gs = cc ^ (rr & 7);
      gload_lds16(Abase + (size_t)rr * Kfull + kt + gs * 8, As + c0 * 8);
    }
#pragma unroll
    for (int it = 0; it < 4; ++it) {
      const int c0 = it * 256 + wave * 64;
      const int idx = c0 + lane;
      const int rr = idx >> 3, cc = idx & 7;
      const int gs = cc ^ (rr & 7);
      gload_lds16(Bbase + (size_t)rr * Kfull + kt + gs * 8, Bs + c0 * 8);
    }
    asm volatile("s_waitcnt vmcnt(0)" ::: "memory");
    __syncthreads();
#pragma unroll
    for (int s = 0; s < 2; ++s) {
      bf16x8 af[4], bfr[4];
#pragma unroll
      for (int mi = 0; mi < 4; ++mi) {
        const int rr = wm * 64 + mi * 16 + r;
        const int ch = (s * 4 + g) ^ (rr & 7);
        af[mi] = *reinterpret_cast<const bf16x8*>(&As[rr * BK + ch * 8]);
      }
#pragma unroll
      for (int ni = 0; ni < 4; ++ni) {
        const int rr = wn * 64 + ni * 16 + r;
        const int ch = (s * 4 + g) ^ (rr & 7);
        bfr[ni] = *reinterpret_cast<const bf16x8*>(&Bs[rr * BK + ch * 8]);
      }
#pragma unroll
      for (int mi = 0; mi < 4; ++mi)
#pragma unroll
        for (int ni = 0; ni < 4; ++ni)
          acc[mi][ni] = __builtin_amdgcn_mfma_f32_16x16x32_bf16(
              af[mi], bfr[ni], acc[mi][ni], 0, 0, 0);
    }
    __syncthreads();
  }

#pragma unroll
  for (int mi = 0; mi < 4; ++mi) {
#pragma unroll
    for (int ni = 0; ni < 4; ++ni) {
      const int grow0 = bm * BM + wm * 64 + mi * 16 + g * 4;
      const int gcol  = bn * BN + wn * 64 + ni * 16 + r;
#pragma unroll
      for (int i = 0; i < 4; ++i) {
        const int grow = grow0 + i;
        const float v = acc[mi][ni][i];
        const size_t o = (size_t)grow * N + gcol;
        if (z == 0) fout[o] = v;
        else {
          bf16_t* pb = (z == 1) ? bout0 : (z == 2) ? bout1 : bout2;
          pb[o] = (bf16_t)v;
        }
      }
    }
  }
}

// ====== split-K attention, 8-wave 128-row blocks, LDS-staged K/V ============

// ---- P1: partial (m, z) per (16-row strip, chunk) ---------------------------
__global__ __launch_bounds__(512, 4) void attn_p1(
    const bf16_t* __restrict__ Q, const bf16_t* __restrict__ Km,
    float2* __restrict__ mzP)
{
  __shared__ bf16_t Ks[2][64 * 64];
  const int tid = threadIdx.x;
  const int w = tid >> 6, lane = tid & 63;
  const int r = lane & 15, g = lane >> 4;
  const int bid = blockIdx.x;
  const int bh  = (bid & 7) * 4 + ((bid >> 3) & 3);
  int gu, c; item40_to_uc(bid >> 5, gu, c);
  const int cmax = gu >> 2;
  const bool diag = (c == cmax);
  const int nt = diag ? ((gu & 3) * 2 + 2) : 8;
  const int s = gu * 8 + w;
  const int qrow = gu * 128 + w * 16 + r;

  const bf16_t* Qh = Q  + (size_t)bh * TT * DH;
  const bf16_t* Kh = Km + (size_t)bh * TT * DH;
  const float SCL = 0.125f * LOG2E;

  bf16x8 qf[2];
#pragma unroll
  for (int s2 = 0; s2 < 2; ++s2) {
    bf16x8 t = *reinterpret_cast<const bf16x8*>(Qh + (size_t)qrow * DH + s2 * 32 + g * 8);
#pragma unroll
    for (int i = 0; i < 8; ++i) t[i] = (bf16_t)((float)t[i] * SCL);
    qf[s2] = t;
  }

  auto STAGEK = [&](int b, int t8) {
    const int rr = tid >> 3, cc = tid & 7, gs = cc ^ (rr & 7);
    gload_lds16(Kh + (size_t)(c * 512 + t8 * 64 + rr) * DH + gs * 8, &Ks[b][tid * 8]);
  };

  float runM = -1e30f, runZ = 0.f;
  STAGEK(0, 0);
  for (int t8 = 0; t8 < nt; ++t8) {
    const int b = t8 & 1;
    asm volatile("s_waitcnt vmcnt(0)" ::: "memory");
    __syncthreads();
    if (t8 + 1 < nt) STAGEK(b ^ 1, t8 + 1);
    f32x4 sfT[4] = {};
#pragma unroll
    for (int s2 = 0; s2 < 2; ++s2) {
      bf16x8 kf[4];
#pragma unroll
      for (int ni = 0; ni < 4; ++ni)
        kf[ni] = *reinterpret_cast<const bf16x8*>(
            &Ks[b][(ni * 16 + r) * 64 + (((s2 << 2) | g) ^ (r & 7)) * 8]);
#pragma unroll
      for (int ni = 0; ni < 4; ++ni)
        sfT[ni] = __builtin_amdgcn_mfma_f32_16x16x32_bf16(kf[ni], qf[s2], sfT[ni], 0, 0, 0);
    }
    const int kbase = c * 512 + t8 * 64;
    float xv[16];
#pragma unroll
    for (int ni = 0; ni < 4; ++ni)
#pragma unroll
      for (int j = 0; j < 4; ++j) {
        float x = sfT[ni][j];
        if (diag) {
          const int kcol = kbase + ni * 16 + g * 4 + j;
          if (kcol > qrow) x = -1e30f;
        }
        xv[ni * 4 + j] = x;
      }
    float nm = runM;
#pragma unroll
    for (int e = 0; e < 16; ++e) nm = fmaxf(nm, xv[e]);
    float z = runZ * fexp2(runM - nm);
#pragma unroll
    for (int e = 0; e < 16; ++e) z += fexp2(xv[e] - nm);
    runM = nm; runZ = z;
  }
#pragma unroll
  for (int msk = 16; msk < 64; msk <<= 1) {
    const float om = __shfl_xor(runM, msk), oz = __shfl_xor(runZ, msk);
    const float nm = fmaxf(runM, om);
    runZ = runZ * fexp2(runM - nm) + oz * fexp2(om - nm);
    runM = nm;
  }
  if (lane < 16)
    mzP[((size_t)(bh * 128 + s) * 4 + c) * 16 + r] = make_float2(runM, runZ);
}

// ---- P3: gated partial yacc/den per chunk -----------------------------------
__global__ __launch_bounds__(512, 2) void attn_p3(
    const bf16_t* __restrict__ Q, const bf16_t* __restrict__ Km,
    const bf16_t* __restrict__ Vt, const float2* __restrict__ mzP,
    bf16_t* __restrict__ Y, uint2* __restrict__ yaccA,
    uint2* __restrict__ yaccB, float* __restrict__ denP,
    const float* __restrict__ thrp, const float* __restrict__ leakp,
    const float* __restrict__ steepp)
{
  __shared__ bf16_t Ks[2][64 * 64];
  __shared__ bf16_t Vs[2][64 * 64];
  __shared__ __align__(16) u32 Ms[8][512];

  const int tid = threadIdx.x;
  const int w = tid >> 6, lane = tid & 63;
  const int r = lane & 15, g = lane >> 4;
  const int bid = blockIdx.x;
  const int bh  = (bid & 7) * 4 + ((bid >> 3) & 3);
  int gu, c; item40_to_uc(bid >> 5, gu, c);
  const int cmax = gu >> 2;
  const bool diag = (c == cmax);
  const int nt = diag ? ((gu & 3) * 2 + 2) : 8;
  const int nch = cmax + 1;
  const int s = gu * 8 + w;
  const int row0w = gu * 128 + w * 16;
  const int qrow = row0w + r;
  const int hh = bh & (NH - 1), bb = bh >> 4;

  const bf16_t* Qh  = Q  + (size_t)bh * TT * DH;
  const bf16_t* Kh  = Km + (size_t)bh * TT * DH;
  const bf16_t* Vth = Vt + (size_t)bh * TT * DH;

  const float lk  = 1.0f / (1.0f + expf(-leakp[hh]));
  const float ilk = 1.0f - lk;
  const float st  = log1pf(expf(steepp[hh]));
  const float Lst = LOG2E * st;
  const float A0  = Lst * (fabsf(thrp[hh]) * 0.1f);

  float M = -1e30f, Z = 0.f;
  for (int c2 = 0; c2 < nch; ++c2) {
    const float2 mz = mzP[((size_t)(bh * 128 + s) * 4 + c2) * 16 + r];
    const float nm = fmaxf(M, mz.x);
    Z = Z * fexp2(M - nm) + mz.y * fexp2(mz.x - nm);
    M = nm;
  }
  const float rcpZ = frcp(Z);

  const float SCL = 0.125f * LOG2E;
  bf16x8 qf[2];
#pragma unroll
  for (int s2 = 0; s2 < 2; ++s2) {
    bf16x8 t = *reinterpret_cast<const bf16x8*>(Qh + (size_t)qrow * DH + s2 * 32 + g * 8);
#pragma unroll
    for (int i = 0; i < 8; ++i) t[i] = (bf16_t)((float)t[i] * SCL);
    qf[s2] = t;
  }
  bf16x8 ones;
#pragma unroll
  for (int i = 0; i < 8; ++i) ones[i] = (bf16_t)1.0f;

  uint2* MsU2 = reinterpret_cast<uint2*>(&Ms[w][0]);
  uint4* MsU4 = reinterpret_cast<uint4*>(&Ms[w][0]);

  auto STAGE = [&](int b, int t8) {
    const int kbase = c * 512 + t8 * 64;
    const int rr = tid >> 3, cc = tid & 7, gs = cc ^ (rr & 7);
    gload_lds16(Kh + (size_t)(kbase + rr) * DH + gs * 8, &Ks[b][tid * 8]);
    gload_lds16(Vth + (size_t)rr * TT + kbase + gs * 8, &Vs[b][tid * 8]);
  };

  f32x4 yacc[4] = {};
  f32x4 dacc = {};

  STAGE(0, 0);
  for (int t8 = 0; t8 < nt; ++t8) {
    const int b = t8 & 1;
    asm volatile("s_waitcnt vmcnt(0)" ::: "memory");
    __syncthreads();
    if (t8 + 1 < nt) STAGE(b ^ 1, t8 + 1);
    const int kbase = c * 512 + t8 * 64;
    f32x4 sfT[4] = {};
#pragma unroll
    for (int s2 = 0; s2 < 2; ++s2) {
      bf16x8 kf[4];
#pragma unroll
      for (int ni = 0; ni < 4; ++ni)
        kf[ni] = *reinterpret_cast<const bf16x8*>(
            &Ks[b][(ni * 16 + r) * 64 + (((s2 << 2) | g) ^ (r & 7)) * 8]);
#pragma unroll
      for (int ni = 0; ni < 4; ++ni)
        sfT[ni] = __builtin_amdgcn_mfma_f32_16x16x32_bf16(kf[ni], qf[s2], sfT[ni], 0, 0, 0);
    }
#pragma unroll
    for (int ni = 0; ni < 4; ++ni) {
      float mv[4];
#pragma unroll
      for (int j = 0; j < 4; ++j) {
        float x = sfT[ni][j];
        if (diag) {
          const int kcol = kbase + ni * 16 + g * 4 + j;
          if (kcol > qrow) x = -1e30f;
        }
        const float p    = fexp2(x - M) * rcpZ;
        const float fire = frcp(1.0f + fexp2(A0 - Lst * p));
        mv[j] = p * fmaf(ilk, fire, lk);
      }
      MsU2[r * 16 + ((4 * ni + g) ^ ((r & 7) << 1))] =
          make_uint2(cvt_pk_bf16(mv[0], mv[1]), cvt_pk_bf16(mv[2], mv[3]));
    }
#pragma unroll
    for (int s2 = 0; s2 < 2; ++s2) {
      const uint4 aw = MsU4[r * 8 + ((s2 * 4 + g) ^ (r & 7))];
      const bf16x8 af = __builtin_bit_cast(bf16x8, aw);
      bf16x8 vf[4];
#pragma unroll
      for (int ni = 0; ni < 4; ++ni)
        vf[ni] = *reinterpret_cast<const bf16x8*>(
            &Vs[b][(ni * 16 + r) * 64 + (((s2 << 2) | g) ^ (r & 7)) * 8]);
#pragma unroll
      for (int ni = 0; ni < 4; ++ni)
        yacc[ni] = __builtin_amdgcn_mfma_f32_16x16x32_bf16(af, vf[ni], yacc[ni], 0, 0, 0);
      dacc = __builtin_amdgcn_mfma_f32_16x16x32_bf16(af, ones, dacc, 0, 0, 0);
    }
  }

  if (nch == 1) {
#pragma unroll
    for (int j = 0; j < 4; ++j) {
      const float rd = frcp(dacc[j] + 1e-8f);
      const int t = row0w + g * 4 + j;
#pragma unroll
      for (int ni = 0; ni < 4; ++ni)
        Y[((size_t)(bb * TT + t)) * C_ + hh * DH + ni * 16 + r] =
            (bf16_t)(yacc[ni][j] * rd);
    }
  } else {
    const int pid = bh * 288 + (sc_to_t(s, c) - 32);
    uint2* pb = (pid < 4096) ? (yaccA + (size_t)pid * 256)
                             : (yaccB + (size_t)(pid - 4096) * 256);
#pragma unroll
    for (int ni = 0; ni < 4; ++ni)
      pb[ni * 64 + lane] =
          make_uint2(cvt_pk_bf16(yacc[ni][0], yacc[ni][1]),
                     cvt_pk_bf16(yacc[ni][2], yacc[ni][3]));
    if (r == 0)
      *reinterpret_cast<float4*>(&denP[(size_t)pid * 16 + g * 4]) =
          make_float4(dacc[0], dacc[1], dacc[2], dacc[3]);
  }
}

// ---- P4: combine chunk partials for strips >= 32 ----------------------------
__global__ __launch_bounds__(256) void attn_p4(
    const uint2* __restrict__ yaccA, const uint2* __restrict__ yaccB,
    const float* __restrict__ denP, bf16_t* __restrict__ Y)
{
  const int bid = blockIdx.x;
  const int bh  = bid / 96;
  const int s   = 32 + (bid - bh * 96);
  const int nch = (s >> 5) + 1;
  const int hh = bh & (NH - 1), bb = bh >> 4;

  const int tid = threadIdx.x;
  const int w = tid >> 6, lane = tid & 63;
  const int r = lane & 15, g = lane >> 4;

  float acc[4] = {};
  float den[4] = {};
  for (int c = 0; c < nch; ++c) {
    const int pid = bh * 288 + (sc_to_t(s, c) - 32);
    const uint2* pb = (pid < 4096) ? (yaccA + (size_t)pid * 256)
                                   : (yaccB + (size_t)(pid - 4096) * 256);
    const uint2 u = pb[w * 64 + lane];
    acc[0] += __builtin_bit_cast(float, (u.x & 0xFFFFu) << 16);
    acc[1] += __builtin_bit_cast(float, (u.x & 0xFFFF0000u));
    acc[2] += __builtin_bit_cast(float, (u.y & 0xFFFFu) << 16);
    acc[3] += __builtin_bit_cast(float, (u.y & 0xFFFF0000u));
    const float4 d4 = *reinterpret_cast<const float4*>(&denP[(size_t)pid * 16 + g * 4]);
    den[0] += d4.x; den[1] += d4.y; den[2] += d4.z; den[3] += d4.w;
  }
#pragma unroll
  for (int j = 0; j < 4; ++j) {
    const float rd = 1.0f / (den[j] + 1e-8f);
    const int t = s * 16 + g * 4 + j;
    Y[((size_t)(bb * TT + t)) * C_ + hh * DH + w * 16 + r] = (bf16_t)(acc[j] * rd);
  }
}

// ---------------------------------------------------------------------------
extern "C" void kernel_launch(void* const* d_in, const int* in_sizes, int n_in,
                              void* d_out, int out_size, void* d_ws, size_t ws_size,
                              hipStream_t stream)
{
  const float* x      = (const float*)d_in[0];
  const float* ln1_w  = (const float*)d_in[1];
  const float* ln1_b  = (const float*)d_in[2];
  const float* w_attn = (const float*)d_in[3];
  const float* b_attn = (const float*)d_in[4];
  const float* w_proj = (const float*)d_in[5];
  const float* b_proj = (const float*)d_in[6];
  const float* thr    = (const float*)d_in[7];
  const float* leak   = (const float*)d_in[8];
  const float* steep  = (const float*)d_in[9];
  const float* ln2_w  = (const float*)d_in[10];
  const float* ln2_b  = (const float*)d_in[11];
  const float* w_fc   = (const float*)d_in[12];
  const float* b_fc   = (const float*)d_in[13];
  const float* w_mlp  = (const float*)d_in[14];
  const float* b_mlp  = (const float*)d_in[15];

  char* ws = (char*)d_ws;
  bf16_t* q    = (bf16_t*)(ws + 0);          //  8 MB
  bf16_t* k    = (bf16_t*)(ws + 8388608);    //  8 MB
  bf16_t* vT   = (bf16_t*)(ws + 25165824);   //  8 MB (written directly by QKV)
  bf16_t* gbuf = (bf16_t*)(ws + 0);          // 32 MB, aliases q/k/vT (dead)
  bf16_t* hbuf = (bf16_t*)(ws + 33554432);   //  8 MB, h -> Y -> h2
  float*  x2   = (float*) (ws + 41943040);   // 16 MB
  bf16_t* wT_attn = (bf16_t*)(ws + 58720256); // 6 MB
  bf16_t* wT_proj = (bf16_t*)(ws + 65011712); // 2 MB
  bf16_t* wT_fc   = (bf16_t*)(ws + 67108864); // 8 MB
  bf16_t* wT_mlp  = (bf16_t*)(ws + 75497472); // 8 MB -> 80 MB total

  // attention scratch (aliases old v-slot and x2-slot, dead during attention)
  uint2* yaccA = (uint2*)(ws + 16777216);
  uint2* yaccB = (uint2*)(ws + 41943040);
  float* denP  = (float*)(ws + 52428800);
  float2* mzP  = (float2*)(ws + 53477376);

  // proj split-K partial (dead q slot)
  bf16_t* pp1 = (bf16_t*)(ws + 0);
  // mlp_proj split-K partials (dead hbuf / wT_attn+wT_proj / wT_fc slots)
  bf16_t* mp1 = (bf16_t*)(ws + 33554432);
  bf16_t* mp2 = (bf16_t*)(ws + 58720256);
  bf16_t* mp3 = (bf16_t*)(ws + 67108864);

  float* out = (float*)d_out;

  ln_bf16<<<dim3(MROWS), dim3(256), 0, stream>>>(x, ln1_w, ln1_b, hbuf);
  transpose_w<<<dim3(96, 32),  dim3(256), 0, stream>>>(w_attn, wT_attn, 1024, 3072);
  transpose_w<<<dim3(32, 32),  dim3(256), 0, stream>>>(w_proj, wT_proj, 1024, 1024);
  transpose_w<<<dim3(128, 32), dim3(256), 0, stream>>>(w_fc,   wT_fc,   1024, 4096);
  transpose_w<<<dim3(32, 128), dim3(256), 0, stream>>>(w_mlp,  wT_mlp,  4096, 1024);

  // QKV: 256x128 tile, 3-buffer counted-vmcnt pipeline; V written transposed
  gemmP<0><<<dim3(384, 1, 1), dim3(512), 0, stream>>>(
      hbuf, wT_attn, b_attn, nullptr, q, k, vT, 3072, 1024, 1024, 24);

  // split-K attention: 8-wave 128-row blocks
  attn_p1<<<dim3(1280), dim3(512), 0, stream>>>(q, k, mzP);
  attn_p3<<<dim3(1280), dim3(512), 0, stream>>>(
      q, k, vT, mzP, hbuf, yaccA, yaccB, denP, thr, leak, steep);
  attn_p4<<<dim3(3072), dim3(256), 0, stream>>>(yaccA, yaccB, denP, hbuf);

  // attn projection, split-K 2: z0 -> raw fp32 in x2, z1 -> bf16 pp1
  gemm_sk<<<dim3(32, 8, 2), dim3(256), 0, stream>>>(
      hbuf, wT_proj, x2, pp1, nullptr, nullptr, MROWS, 1024, 512, 1024);

  // LN2 fused with proj combine
  ln2_fuse<<<dim3(MROWS), dim3(256), 0, stream>>>(
      x2, pp1, x, b_proj, ln2_w, ln2_b, x2, hbuf);

  // MLP fc + GELU: 256x128 tile pipeline
  gemmP<2><<<dim3(512, 1, 1), dim3(512), 0, stream>>>(
      hbuf, wT_fc, b_fc, nullptr, gbuf, nullptr, nullptr, 4096, 1024, 1024, 32);

  // MLP proj, split-K 4: z0 -> raw fp32 in out, z1-3 -> bf16 mp1..3
  gemm_sk<<<dim3(32, 8, 4), dim3(256), 0, stream>>>(
      gbuf, wT_mlp, out, mp1, mp2, mp3, MROWS, 1024, 1024, 4096);

  // final combine: out += mp1+mp2+mp3 + b_mlp + x2
  combine3<<<dim3(4096), dim3(256), 0, stream>>>(out, mp1, mp2, mp3, b_mlp, x2);
}

// Round 13
// 288.212 us; speedup vs baseline: 1.0735x; 1.0735x over previous
//
#include <hip/hip_runtime.h>
#include <hip/hip_bf16.h>
#include <math.h>

typedef __bf16 bf16_t;
typedef __bf16 bf16x8 __attribute__((ext_vector_type(8)));
typedef __bf16 bf16x4 __attribute__((ext_vector_type(4)));
typedef float  f32x4  __attribute__((ext_vector_type(4)));
typedef unsigned int u32;

static constexpr int C_    = 1024;
static constexpr int NH    = 16;
static constexpr int DH    = 64;
static constexpr int BB    = 2;
static constexpr int TT    = 2048;
static constexpr int MROWS = BB * TT;   // 4096
static constexpr float LOG2E = 1.4426950408889634f;

// ---------------- helpers ----------------------------------------------------
__device__ __forceinline__ void gload_lds16(const bf16_t* src, bf16_t* dst) {
  __builtin_amdgcn_global_load_lds(
      (const __attribute__((address_space(1))) u32*)(src),
      (__attribute__((address_space(3))) u32*)(dst),
      16, 0, 0);
}

__device__ __forceinline__ u32 cvt_pk_bf16(float a, float b) {
  u32 r;
  asm("v_cvt_pk_bf16_f32 %0, %1, %2" : "=v"(r) : "v"(a), "v"(b));
  return r;
}

__device__ __forceinline__ float fexp2(float x) {
#if __has_builtin(__builtin_amdgcn_exp2f)
  return __builtin_amdgcn_exp2f(x);
#else
  return exp2f(x);
#endif
}
__device__ __forceinline__ float frcp(float x) {
#if __has_builtin(__builtin_amdgcn_rcpf)
  return __builtin_amdgcn_rcpf(x);
#else
  return 1.0f / x;
#endif
}

// cumulative item index for strip-of-16 s and chunk c (pid scheme, P4)
__device__ __forceinline__ int sc_to_t(int s, int c) {
  if (s < 32)  return s;
  if (s < 64)  return 32 + (s - 32) * 2 + c;
  if (s < 96)  return 96 + (s - 64) * 3 + c;
  return 192 + (s - 96) * 4 + c;
}

// block item (64-row group) mapping: item in [0,80) -> (u in [0,32), c)
__device__ __forceinline__ void item64_to_uc(int item, int& u, int& c) {
  if (item < 8)       { u = item;               c = 0; }
  else if (item < 24) { int v = item - 8;  u = 8  + (v >> 1); c = v & 1; }
  else if (item < 48) { int v = item - 24; u = 16 + v / 3;    c = v - 3 * (v / 3); }
  else                { int v = item - 48; u = 24 + (v >> 2); c = v & 3; }
}

// ---------------- fused prep: LN1 (blocks 0..4095) + 4 weight transposes ----
__global__ __launch_bounds__(256) void prep(
    const float* __restrict__ x, const float* __restrict__ ln1_w,
    const float* __restrict__ ln1_b, bf16_t* __restrict__ hout,
    const float* __restrict__ w_attn, bf16_t* __restrict__ wT_attn,
    const float* __restrict__ w_proj, bf16_t* __restrict__ wT_proj,
    const float* __restrict__ w_fc,   bf16_t* __restrict__ wT_fc,
    const float* __restrict__ w_mlp,  bf16_t* __restrict__ wT_mlp)
{
  const int bid = blockIdx.x;
  const int tid = threadIdx.x;
  if (bid < MROWS) {
    // ---- LayerNorm row ----
    const int row = bid;
    const float4 v = reinterpret_cast<const float4*>(x + (size_t)row * C_)[tid];
    float s  = v.x + v.y + v.z + v.w;
    float s2 = v.x*v.x + v.y*v.y + v.z*v.z + v.w*v.w;
#pragma unroll
    for (int m = 1; m < 64; m <<= 1) { s += __shfl_xor(s, m); s2 += __shfl_xor(s2, m); }
    __shared__ float red[8];
    const int wv = tid >> 6;
    if ((tid & 63) == 0) { red[wv] = s; red[4 + wv] = s2; }
    __syncthreads();
    s  = red[0] + red[1] + red[2] + red[3];
    s2 = red[4] + red[5] + red[6] + red[7];
    const float mu   = s * (1.0f / C_);
    const float rstd = rsqrtf(s2 * (1.0f / C_) - mu * mu + 1e-5f);
    const float4 wv4 = reinterpret_cast<const float4*>(ln1_w)[tid];
    const float4 bv4 = reinterpret_cast<const float4*>(ln1_b)[tid];
    bf16x4 o;
    o[0] = (bf16_t)((v.x - mu) * rstd * wv4.x + bv4.x);
    o[1] = (bf16_t)((v.y - mu) * rstd * wv4.y + bv4.y);
    o[2] = (bf16_t)((v.z - mu) * rstd * wv4.z + bv4.z);
    o[3] = (bf16_t)((v.w - mu) * rstd * wv4.w + bv4.w);
    *reinterpret_cast<bf16x4*>(hout + (size_t)row * C_ + tid * 4) = o;
    return;
  }
  // ---- weight transpose block ----
  int tb = bid - MROWS;
  const float* in; bf16_t* out; int K, N, nbx;
  if (tb < 3072)      { in = w_attn; out = wT_attn; K = 1024; N = 3072; nbx = 96; }
  else if (tb < 4096) { tb -= 3072; in = w_proj; out = wT_proj; K = 1024; N = 1024; nbx = 32; }
  else if (tb < 8192) { tb -= 4096; in = w_fc;   out = wT_fc;   K = 1024; N = 4096; nbx = 128; }
  else                { tb -= 8192; in = w_mlp;  out = wT_mlp;  K = 4096; N = 1024; nbx = 32; }
  const int n0 = (tb % nbx) * 32, k0 = (tb / nbx) * 32;
  __shared__ float tile[32][33];
  const int tx = tid & 31, ty = tid >> 5;
#pragma unroll
  for (int i = 0; i < 4; ++i)
    tile[ty + i * 8][tx] = in[(size_t)(k0 + ty + i * 8) * N + n0 + tx];
  __syncthreads();
#pragma unroll
  for (int i = 0; i < 4; ++i)
    out[(size_t)(n0 + ty + i * 8) * K + k0 + tx] = (bf16_t)tile[tx][ty + i * 8];
}

// ---------------- LN2 fused with proj split-K combine ------------------------
__global__ __launch_bounds__(256) void ln2_fuse(
    const float* __restrict__ p0, const bf16_t* __restrict__ p1,
    const float* __restrict__ xin, const float* __restrict__ pbias,
    const float* __restrict__ w, const float* __restrict__ b,
    float* __restrict__ x2out, bf16_t* __restrict__ out)
{
  const int row = blockIdx.x;
  const int tid = threadIdx.x;
  const size_t base = (size_t)row * C_ + tid * 4;
  const float4 v0 = *reinterpret_cast<const float4*>(p0 + base);
  const bf16x4 v1 = *reinterpret_cast<const bf16x4*>(p1 + base);
  const float4 xr = *reinterpret_cast<const float4*>(xin + base);
  const float4 pb = *reinterpret_cast<const float4*>(pbias + tid * 4);
  float4 v;
  v.x = v0.x + (float)v1[0] + pb.x + xr.x;
  v.y = v0.y + (float)v1[1] + pb.y + xr.y;
  v.z = v0.z + (float)v1[2] + pb.z + xr.z;
  v.w = v0.w + (float)v1[3] + pb.w + xr.w;
  *reinterpret_cast<float4*>(x2out + base) = v;

  float s  = v.x + v.y + v.z + v.w;
  float s2 = v.x*v.x + v.y*v.y + v.z*v.z + v.w*v.w;
#pragma unroll
  for (int m = 1; m < 64; m <<= 1) { s += __shfl_xor(s, m); s2 += __shfl_xor(s2, m); }
  __shared__ float red[8];
  const int wv = tid >> 6;
  if ((tid & 63) == 0) { red[wv] = s; red[4 + wv] = s2; }
  __syncthreads();
  s  = red[0] + red[1] + red[2] + red[3];
  s2 = red[4] + red[5] + red[6] + red[7];
  const float mu   = s * (1.0f / C_);
  const float rstd = rsqrtf(s2 * (1.0f / C_) - mu * mu + 1e-5f);
  const float4 wv4 = reinterpret_cast<const float4*>(w)[tid];
  const float4 bv4 = reinterpret_cast<const float4*>(b)[tid];
  bf16x4 o;
  o[0] = (bf16_t)((v.x - mu) * rstd * wv4.x + bv4.x);
  o[1] = (bf16_t)((v.y - mu) * rstd * wv4.y + bv4.y);
  o[2] = (bf16_t)((v.z - mu) * rstd * wv4.z + bv4.z);
  o[3] = (bf16_t)((v.w - mu) * rstd * wv4.w + bv4.w);
  *reinterpret_cast<bf16x4*>(out + base) = o;
}

// ---------------- combine for mlp_proj split-K -------------------------------
__global__ __launch_bounds__(256) void combine3(
    float* __restrict__ out, const bf16_t* __restrict__ p1,
    const bf16_t* __restrict__ p2, const bf16_t* __restrict__ p3,
    const float* __restrict__ bias, const float* __restrict__ resid)
{
  const size_t idx = ((size_t)blockIdx.x * 256 + threadIdx.x) * 4;
  float4 o = *reinterpret_cast<const float4*>(out + idx);
  const bf16x4 a = *reinterpret_cast<const bf16x4*>(p1 + idx);
  const bf16x4 b = *reinterpret_cast<const bf16x4*>(p2 + idx);
  const bf16x4 c = *reinterpret_cast<const bf16x4*>(p3 + idx);
  const float4 r = *reinterpret_cast<const float4*>(resid + idx);
  const int col = (int)(idx & (C_ - 1));
  const float4 bv = *reinterpret_cast<const float4*>(bias + col);
  o.x += (float)a[0] + (float)b[0] + (float)c[0] + bv.x + r.x;
  o.y += (float)a[1] + (float)b[1] + (float)c[1] + bv.y + r.y;
  o.z += (float)a[2] + (float)b[2] + (float)c[2] + bv.z + r.z;
  o.w += (float)a[3] + (float)b[3] + (float)c[3] + bv.w + r.w;
  *reinterpret_cast<float4*>(out + idx) = o;
}

// ---------------- V transpose: bf16 [BH][T][D] -> [BH][D][T] -----------------
__global__ __launch_bounds__(256) void transpose_v(
    const bf16_t* __restrict__ in, bf16_t* __restrict__ out)
{
  __shared__ bf16_t tile[32][33];
  const int bh = blockIdx.z;
  const bf16_t* src = in  + (size_t)bh * TT * DH;
  bf16_t*       dst = out + (size_t)bh * TT * DH;
  const int tx = threadIdx.x & 31, ty = threadIdx.x >> 5;
  const int t0 = blockIdx.x * 32, d0 = blockIdx.y * 32;
#pragma unroll
  for (int i = 0; i < 4; ++i)
    tile[ty + i * 8][tx] = src[(size_t)(t0 + ty + i * 8) * DH + d0 + tx];
  __syncthreads();
#pragma unroll
  for (int i = 0; i < 4; ++i)
    dst[(size_t)(d0 + ty + i * 8) * TT + t0 + tx] = tile[tx][ty + i * 8];
}

// ---------------- 256x128 GEMM, 8 waves, 3-buffer LDS, counted vmcnt ---------
// EPI 0: +bias qkv scatter  EPI 2: +bias gelu bf16
template<int EPI>
__global__ __launch_bounds__(512, 1) void gemmP(
    const bf16_t* __restrict__ A, const bf16_t* __restrict__ Bt,
    const float* __restrict__ bias, float* __restrict__ fout,
    bf16_t* __restrict__ bout0, bf16_t* __restrict__ bout1,
    bf16_t* __restrict__ bout2, int N, int Kc, int Kfull, int nbn)
{
  __shared__ bf16_t As[3][256 * 64];   // 96 KB
  __shared__ bf16_t Bs[3][128 * 64];   // 48 KB
  const int tid  = threadIdx.x;
  const int wave = tid >> 6, lane = tid & 63;
  const int r = lane & 15, g = lane >> 4;
  const int wm = wave >> 2, wn = wave & 3;   // 2 x 4 waves: 128 x 32 per wave

  const int cpx = gridDim.x >> 3;
  const int swz = (blockIdx.x & 7) * cpx + (blockIdx.x >> 3);
  const int bm = swz / nbn, bn = swz - bm * nbn;
  const int k0 = 0;

  const bf16_t* Abase = A  + (size_t)bm * 256 * Kfull + k0;
  const bf16_t* Bbase = Bt + (size_t)bn * 128 * Kfull + k0;

  f32x4 acc[8][2] = {};

  auto STG_A = [&](int buf, int kt, int pass) {
    const int idx = pass * 512 + tid;
    const int rr = idx >> 3, cc = idx & 7, gs = cc ^ (rr & 7);
    gload_lds16(Abase + (size_t)rr * Kfull + kt + gs * 8, &As[buf][idx * 8]);
  };
  auto STG_B = [&](int buf, int kt, int pass) {
    const int idx = pass * 512 + tid;
    const int rr = idx >> 3, cc = idx & 7, gs = cc ^ (rr & 7);
    gload_lds16(Bbase + (size_t)rr * Kfull + kt + gs * 8, &Bs[buf][idx * 8]);
  };
  auto STAGE6 = [&](int buf, int kt) {
    STG_A(buf, kt, 0); STG_A(buf, kt, 1);
    STG_A(buf, kt, 2); STG_A(buf, kt, 3);
    STG_B(buf, kt, 0); STG_B(buf, kt, 1);
  };

  const int NT = Kc >> 6;
  STAGE6(0, 0);
  STAGE6(1, 64);

  for (int t = 0; t < NT; ++t) {
    const int buf = t % 3;
    if (t + 1 < NT) asm volatile("s_waitcnt vmcnt(6)" ::: "memory");
    else            asm volatile("s_waitcnt vmcnt(0)" ::: "memory");
    __builtin_amdgcn_s_barrier();
    asm volatile("" ::: "memory");

    const bool pre = (t + 2 < NT);
    const int kn   = (t + 2) << 6;
    const int bnx  = (t + 2) % 3;

    bf16x8 bfr[2][2];
#pragma unroll
    for (int s2 = 0; s2 < 2; ++s2)
#pragma unroll
      for (int ni = 0; ni < 2; ++ni) {
        const int rr = wn * 32 + ni * 16 + r;
        bfr[s2][ni] = *reinterpret_cast<const bf16x8*>(
            &Bs[buf][rr * 64 + (((s2 << 2) | g) ^ (rr & 7)) * 8]);
      }
#pragma unroll
    for (int mh = 0; mh < 2; ++mh) {
      bf16x8 af[2][4];
#pragma unroll
      for (int s2 = 0; s2 < 2; ++s2)
#pragma unroll
        for (int mi = 0; mi < 4; ++mi) {
          const int rr = wm * 128 + (mh * 4 + mi) * 16 + r;
          af[s2][mi] = *reinterpret_cast<const bf16x8*>(
              &As[buf][rr * 64 + (((s2 << 2) | g) ^ (rr & 7)) * 8]);
        }
      if (pre) {
        if (mh == 0) { STG_A(bnx, kn, 0); STG_A(bnx, kn, 1); STG_A(bnx, kn, 2); }
        else         { STG_A(bnx, kn, 3); STG_B(bnx, kn, 0); STG_B(bnx, kn, 1); }
      }
      __builtin_amdgcn_s_setprio(1);
#pragma unroll
      for (int s2 = 0; s2 < 2; ++s2)
#pragma unroll
        for (int mi = 0; mi < 4; ++mi)
#pragma unroll
          for (int ni = 0; ni < 2; ++ni)
            acc[mh * 4 + mi][ni] = __builtin_amdgcn_mfma_f32_16x16x32_bf16(
                af[s2][mi], bfr[s2][ni], acc[mh * 4 + mi][ni], 0, 0, 0);
      __builtin_amdgcn_s_setprio(0);
    }
  }

#pragma unroll
  for (int mi = 0; mi < 8; ++mi) {
#pragma unroll
    for (int ni = 0; ni < 2; ++ni) {
      const int grow0 = bm * 256 + wm * 128 + mi * 16 + g * 4;
      const int gcol  = bn * 128 + wn * 32 + ni * 16 + r;
      const float bv = bias[gcol];
#pragma unroll
      for (int i = 0; i < 4; ++i) {
        const int grow = grow0 + i;
        const float v = acc[mi][ni][i] + bv;
        if constexpr (EPI == 0) {
          const int which = gcol >> 10;
          const int c0 = gcol & 1023;
          const int hh = c0 >> 6, dd = c0 & 63;
          const int bb = grow >> 11, tt = grow & 2047;
          bf16_t* dst = (which == 0) ? bout0 : (which == 1) ? bout1 : bout2;
          dst[((size_t)(bb * NH + hh) * TT + tt) * DH + dd] = (bf16_t)v;
        } else {
          const float gl = 0.5f * v * (1.0f + erff(v * 0.70710678118654752f));
          bout0[(size_t)grow * N + gcol] = (bf16_t)gl;
        }
      }
    }
  }
}

// ---------------- 128x128 GEMM (split-K raw partial epilogue) ---------------
__global__ __launch_bounds__(256) void gemm_sk(
    const bf16_t* __restrict__ A, const bf16_t* __restrict__ Bt,
    float* __restrict__ fout, bf16_t* __restrict__ bout0,
    bf16_t* __restrict__ bout1, bf16_t* __restrict__ bout2,
    int M, int N, int Kc, int Kfull)
{
  constexpr int BM = 128, BN = 128, BK = 64;
  __shared__ bf16_t As[BM * BK];
  __shared__ bf16_t Bs[BN * BK];
  const int tid  = threadIdx.x;
  const int wave = tid >> 6, lane = tid & 63;
  const int r = lane & 15, g = lane >> 4;
  const int wm = wave >> 1, wn = wave & 1;
  const int bm = blockIdx.x, bn = blockIdx.y;
  const int z  = blockIdx.z;
  const int kstart = z * Kc;

  const bf16_t* Abase = A  + (size_t)bm * BM * Kfull;
  const bf16_t* Bbase = Bt + (size_t)bn * BN * Kfull;

  f32x4 acc[4][4] = {};

  for (int kt = kstart; kt < kstart + Kc; kt += BK) {
#pragma unroll
    for (int it = 0; it < 4; ++it) {
      const int c0 = it * 256 + wave * 64;
      const int idx = c0 + lane;
      const int rr = idx >> 3, cc = idx & 7;
      const int gs = cc ^ (rr & 7);
      gload_lds16(Abase + (size_t)rr * Kfull + kt + gs * 8, As + c0 * 8);
    }
#pragma unroll
    for (int it = 0; it < 4; ++it) {
      const int c0 = it * 256 + wave * 64;
      const int idx = c0 + lane;
      const int rr = idx >> 3, cc = idx & 7;
      const int gs = cc ^ (rr & 7);
      gload_lds16(Bbase + (size_t)rr * Kfull + kt + gs * 8, Bs + c0 * 8);
    }
    asm volatile("s_waitcnt vmcnt(0)" ::: "memory");
    __syncthreads();
#pragma unroll
    for (int s = 0; s < 2; ++s) {
      bf16x8 af[4], bfr[4];
#pragma unroll
      for (int mi = 0; mi < 4; ++mi) {
        const int rr = wm * 64 + mi * 16 + r;
        const int ch = (s * 4 + g) ^ (rr & 7);
        af[mi] = *reinterpret_cast<const bf16x8*>(&As[rr * BK + ch * 8]);
      }
#pragma unroll
      for (int ni = 0; ni < 4; ++ni) {
        const int rr = wn * 64 + ni * 16 + r;
        const int ch = (s * 4 + g) ^ (rr & 7);
        bfr[ni] = *reinterpret_cast<const bf16x8*>(&Bs[rr * BK + ch * 8]);
      }
#pragma unroll
      for (int mi = 0; mi < 4; ++mi)
#pragma unroll
        for (int ni = 0; ni < 4; ++ni)
          acc[mi][ni] = __builtin_amdgcn_mfma_f32_16x16x32_bf16(
              af[mi], bfr[ni], acc[mi][ni], 0, 0, 0);
    }
    __syncthreads();
  }

#pragma unroll
  for (int mi = 0; mi < 4; ++mi) {
#pragma unroll
    for (int ni = 0; ni < 4; ++ni) {
      const int grow0 = bm * BM + wm * 64 + mi * 16 + g * 4;
      const int gcol  = bn * BN + wn * 64 + ni * 16 + r;
#pragma unroll
      for (int i = 0; i < 4; ++i) {
        const int grow = grow0 + i;
        const float v = acc[mi][ni][i];
        const size_t o = (size_t)grow * N + gcol;
        if (z == 0) fout[o] = v;
        else {
          bf16_t* pb = (z == 1) ? bout0 : (z == 2) ? bout1 : bout2;
          pb[o] = (bf16_t)v;
        }
      }
    }
  }
}

// ====== split-K attention, 4-wave 64-row blocks, LDS-staged K/V =============

// ---- P1: partial (m, z) per (16-row strip, chunk) ---------------------------
__global__ __launch_bounds__(256, 4) void attn_p1(
    const bf16_t* __restrict__ Q, const bf16_t* __restrict__ Km,
    float2* __restrict__ mzP)
{
  __shared__ bf16_t Ks[2][64 * 64];
  const int tid = threadIdx.x;
  const int w = tid >> 6, lane = tid & 63;
  const int r = lane & 15, g = lane >> 4;
  const int bid = blockIdx.x;
  const int bh  = (bid & 7) * 4 + ((bid >> 3) & 3);
  int u, c; item64_to_uc(bid >> 5, u, c);
  const int cmax = u >> 3;
  const bool diag = (c == cmax);
  const int nt = diag ? (u & 7) + 1 : 8;
  const int s = 4 * u + w;
  const int row0 = u * 64 + w * 16;
  const int qrow = row0 + r;

  const bf16_t* Qh = Q  + (size_t)bh * TT * DH;
  const bf16_t* Kh = Km + (size_t)bh * TT * DH;
  const float SCL = 0.125f * LOG2E;

  bf16x8 qf[2];
#pragma unroll
  for (int s2 = 0; s2 < 2; ++s2) {
    bf16x8 t = *reinterpret_cast<const bf16x8*>(Qh + (size_t)qrow * DH + s2 * 32 + g * 8);
#pragma unroll
    for (int i = 0; i < 8; ++i) t[i] = (bf16_t)((float)t[i] * SCL);
    qf[s2] = t;
  }

  auto STAGEK = [&](int b, int t8) {
#pragma unroll
    for (int it = 0; it < 2; ++it) {
      const int idx = it * 256 + tid;
      const int rr = idx >> 3, cc = idx & 7, gs = cc ^ (rr & 7);
      gload_lds16(Kh + (size_t)(c * 512 + t8 * 64 + rr) * DH + gs * 8, &Ks[b][idx * 8]);
    }
  };

  float runM = -1e30f, runZ = 0.f;
  STAGEK(0, 0);
  for (int t8 = 0; t8 < nt; ++t8) {
    const int b = t8 & 1;
    asm volatile("s_waitcnt vmcnt(0)" ::: "memory");
    __syncthreads();
    if (t8 + 1 < nt) STAGEK(b ^ 1, t8 + 1);
    f32x4 sfT[4] = {};
#pragma unroll
    for (int s2 = 0; s2 < 2; ++s2) {
      bf16x8 kf[4];
#pragma unroll
      for (int ni = 0; ni < 4; ++ni)
        kf[ni] = *reinterpret_cast<const bf16x8*>(
            &Ks[b][(ni * 16 + r) * 64 + (((s2 << 2) | g) ^ (r & 7)) * 8]);
#pragma unroll
      for (int ni = 0; ni < 4; ++ni)
        sfT[ni] = __builtin_amdgcn_mfma_f32_16x16x32_bf16(kf[ni], qf[s2], sfT[ni], 0, 0, 0);
    }
    const bool dm = diag && (t8 == nt - 1);
    const int kbase = c * 512 + t8 * 64;
    float xv[16];
#pragma unroll
    for (int ni = 0; ni < 4; ++ni)
#pragma unroll
      for (int j = 0; j < 4; ++j) {
        float x = sfT[ni][j];
        if (dm) {
          const int kcol = kbase + ni * 16 + g * 4 + j;
          if (kcol > qrow) x = -1e30f;
        }
        xv[ni * 4 + j] = x;
      }
    float nm = runM;
#pragma unroll
    for (int e = 0; e < 16; ++e) nm = fmaxf(nm, xv[e]);
    float z = runZ * fexp2(runM - nm);
#pragma unroll
    for (int e = 0; e < 16; ++e) z += fexp2(xv[e] - nm);
    runM = nm; runZ = z;
  }
#pragma unroll
  for (int msk = 16; msk < 64; msk <<= 1) {
    const float om = __shfl_xor(runM, msk), oz = __shfl_xor(runZ, msk);
    const float nm = fmaxf(runM, om);
    runZ = runZ * fexp2(runM - nm) + oz * fexp2(om - nm);
    runM = nm;
  }
  if (lane < 16)
    mzP[((size_t)(bh * 128 + s) * 4 + c) * 16 + r] = make_float2(runM, runZ);
}

// ---- P3: gated partial yacc/den per chunk -----------------------------------
__global__ __launch_bounds__(256, 4) void attn_p3(
    const bf16_t* __restrict__ Q, const bf16_t* __restrict__ Km,
    const bf16_t* __restrict__ Vt, const float2* __restrict__ mzP,
    bf16_t* __restrict__ Y, uint2* __restrict__ yaccA,
    uint2* __restrict__ yaccB, float* __restrict__ denP,
    const float* __restrict__ thrp, const float* __restrict__ leakp,
    const float* __restrict__ steepp)
{
  __shared__ bf16_t Ks[2][64 * 64];
  __shared__ bf16_t Vs[2][64 * 64];
  __shared__ __align__(16) u32 Ms[4][512];

  const int tid = threadIdx.x;
  const int w = tid >> 6, lane = tid & 63;
  const int r = lane & 15, g = lane >> 4;
  const int bid = blockIdx.x;
  const int bh  = (bid & 7) * 4 + ((bid >> 3) & 3);
  int u, c; item64_to_uc(bid >> 5, u, c);
  const int cmax = u >> 3;
  const bool diag = (c == cmax);
  const int nt = diag ? (u & 7) + 1 : 8;
  const int nch = cmax + 1;
  const int s = 4 * u + w;
  const int row0 = u * 64 + w * 16;
  const int qrow = row0 + r;
  const int hh = bh & (NH - 1), bb = bh >> 4;

  const bf16_t* Qh  = Q  + (size_t)bh * TT * DH;
  const bf16_t* Kh  = Km + (size_t)bh * TT * DH;
  const bf16_t* Vth = Vt + (size_t)bh * TT * DH;

  const float lk  = 1.0f / (1.0f + expf(-leakp[hh]));
  const float ilk = 1.0f - lk;
  const float st  = log1pf(expf(steepp[hh]));
  const float Lst = LOG2E * st;
  const float A0  = Lst * (fabsf(thrp[hh]) * 0.1f);

  float M = -1e30f, Z = 0.f;
  for (int c2 = 0; c2 < nch; ++c2) {
    const float2 mz = mzP[((size_t)(bh * 128 + s) * 4 + c2) * 16 + r];
    const float nm = fmaxf(M, mz.x);
    Z = Z * fexp2(M - nm) + mz.y * fexp2(mz.x - nm);
    M = nm;
  }
  const float rcpZ = frcp(Z);

  const float SCL = 0.125f * LOG2E;
  bf16x8 qf[2];
#pragma unroll
  for (int s2 = 0; s2 < 2; ++s2) {
    bf16x8 t = *reinterpret_cast<const bf16x8*>(Qh + (size_t)qrow * DH + s2 * 32 + g * 8);
#pragma unroll
    for (int i = 0; i < 8; ++i) t[i] = (bf16_t)((float)t[i] * SCL);
    qf[s2] = t;
  }
  bf16x8 ones;
#pragma unroll
  for (int i = 0; i < 8; ++i) ones[i] = (bf16_t)1.0f;

  uint2* MsU2 = reinterpret_cast<uint2*>(&Ms[w][0]);
  uint4* MsU4 = reinterpret_cast<uint4*>(&Ms[w][0]);

  auto STAGE = [&](int b, int t8) {
    const int kbase = c * 512 + t8 * 64;
#pragma unroll
    for (int it = 0; it < 2; ++it) {
      const int idx = it * 256 + tid;
      const int rr = idx >> 3, cc = idx & 7, gs = cc ^ (rr & 7);
      gload_lds16(Kh + (size_t)(kbase + rr) * DH + gs * 8, &Ks[b][idx * 8]);
      gload_lds16(Vth + (size_t)rr * TT + kbase + gs * 8, &Vs[b][idx * 8]);
    }
  };

  f32x4 yacc[4] = {};
  f32x4 dacc = {};

  STAGE(0, 0);
  for (int t8 = 0; t8 < nt; ++t8) {
    const int b = t8 & 1;
    asm volatile("s_waitcnt vmcnt(0)" ::: "memory");
    __syncthreads();
    if (t8 + 1 < nt) STAGE(b ^ 1, t8 + 1);
    const int kbase = c * 512 + t8 * 64;
    f32x4 sfT[4] = {};
#pragma unroll
    for (int s2 = 0; s2 < 2; ++s2) {
      bf16x8 kf[4];
#pragma unroll
      for (int ni = 0; ni < 4; ++ni)
        kf[ni] = *reinterpret_cast<const bf16x8*>(
            &Ks[b][(ni * 16 + r) * 64 + (((s2 << 2) | g) ^ (r & 7)) * 8]);
#pragma unroll
      for (int ni = 0; ni < 4; ++ni)
        sfT[ni] = __builtin_amdgcn_mfma_f32_16x16x32_bf16(kf[ni], qf[s2], sfT[ni], 0, 0, 0);
    }
    const bool dm = diag && (t8 == nt - 1);
#pragma unroll
    for (int ni = 0; ni < 4; ++ni) {
      float mv[4];
#pragma unroll
      for (int j = 0; j < 4; ++j) {
        float x = sfT[ni][j];
        if (dm) {
          const int kcol = kbase + ni * 16 + g * 4 + j;
          if (kcol > qrow) x = -1e30f;
        }
        const float p    = fexp2(x - M) * rcpZ;
        const float fire = frcp(1.0f + fexp2(A0 - Lst * p));
        mv[j] = p * fmaf(ilk, fire, lk);
      }
      MsU2[r * 16 + ((4 * ni + g) ^ ((r & 7) << 1))] =
          make_uint2(cvt_pk_bf16(mv[0], mv[1]), cvt_pk_bf16(mv[2], mv[3]));
    }
#pragma unroll
    for (int s2 = 0; s2 < 2; ++s2) {
      const uint4 aw = MsU4[r * 8 + ((s2 * 4 + g) ^ (r & 7))];
      const bf16x8 af = __builtin_bit_cast(bf16x8, aw);
      bf16x8 vf[4];
#pragma unroll
      for (int ni = 0; ni < 4; ++ni)
        vf[ni] = *reinterpret_cast<const bf16x8*>(
            &Vs[b][(ni * 16 + r) * 64 + (((s2 << 2) | g) ^ (r & 7)) * 8]);
#pragma unroll
      for (int ni = 0; ni < 4; ++ni)
        yacc[ni] = __builtin_amdgcn_mfma_f32_16x16x32_bf16(af, vf[ni], yacc[ni], 0, 0, 0);
      dacc = __builtin_amdgcn_mfma_f32_16x16x32_bf16(af, ones, dacc, 0, 0, 0);
    }
  }

  if (nch == 1) {
#pragma unroll
    for (int j = 0; j < 4; ++j) {
      const float rd = frcp(dacc[j] + 1e-8f);
      const int t = row0 + g * 4 + j;
#pragma unroll
      for (int ni = 0; ni < 4; ++ni)
        Y[((size_t)(bb * TT + t)) * C_ + hh * DH + ni * 16 + r] =
            (bf16_t)(yacc[ni][j] * rd);
    }
  } else {
    const int pid = bh * 288 + (sc_to_t(s, c) - 32);
    uint2* pb = (pid < 4096) ? (yaccA + (size_t)pid * 256)
                             : (yaccB + (size_t)(pid - 4096) * 256);
#pragma unroll
    for (int ni = 0; ni < 4; ++ni)
      pb[ni * 64 + lane] =
          make_uint2(cvt_pk_bf16(yacc[ni][0], yacc[ni][1]),
                     cvt_pk_bf16(yacc[ni][2], yacc[ni][3]));
    if (r == 0)
      *reinterpret_cast<float4*>(&denP[(size_t)pid * 16 + g * 4]) =
          make_float4(dacc[0], dacc[1], dacc[2], dacc[3]);
  }
}

// ---- P4: combine chunk partials for strips >= 32 ----------------------------
__global__ __launch_bounds__(256) void attn_p4(
    const uint2* __restrict__ yaccA, const uint2* __restrict__ yaccB,
    const float* __restrict__ denP, bf16_t* __restrict__ Y)
{
  const int bid = blockIdx.x;
  const int bh  = bid / 96;
  const int s   = 32 + (bid - bh * 96);
  const int nch = (s >> 5) + 1;
  const int hh = bh & (NH - 1), bb = bh >> 4;

  const int tid = threadIdx.x;
  const int w = tid >> 6, lane = tid & 63;
  const int r = lane & 15, g = lane >> 4;

  float acc[4] = {};
  float den[4] = {};
  for (int c = 0; c < nch; ++c) {
    const int pid = bh * 288 + (sc_to_t(s, c) - 32);
    const uint2* pb = (pid < 4096) ? (yaccA + (size_t)pid * 256)
                                   : (yaccB + (size_t)(pid - 4096) * 256);
    const uint2 u = pb[w * 64 + lane];
    acc[0] += __builtin_bit_cast(float, (u.x & 0xFFFFu) << 16);
    acc[1] += __builtin_bit_cast(float, (u.x & 0xFFFF0000u));
    acc[2] += __builtin_bit_cast(float, (u.y & 0xFFFFu) << 16);
    acc[3] += __builtin_bit_cast(float, (u.y & 0xFFFF0000u));
    const float4 d4 = *reinterpret_cast<const float4*>(&denP[(size_t)pid * 16 + g * 4]);
    den[0] += d4.x; den[1] += d4.y; den[2] += d4.z; den[3] += d4.w;
  }
#pragma unroll
  for (int j = 0; j < 4; ++j) {
    const float rd = 1.0f / (den[j] + 1e-8f);
    const int t = s * 16 + g * 4 + j;
    Y[((size_t)(bb * TT + t)) * C_ + hh * DH + w * 16 + r] = (bf16_t)(acc[j] * rd);
  }
}

// ---------------------------------------------------------------------------
extern "C" void kernel_launch(void* const* d_in, const int* in_sizes, int n_in,
                              void* d_out, int out_size, void* d_ws, size_t ws_size,
                              hipStream_t stream)
{
  const float* x      = (const float*)d_in[0];
  const float* ln1_w  = (const float*)d_in[1];
  const float* ln1_b  = (const float*)d_in[2];
  const float* w_attn = (const float*)d_in[3];
  const float* b_attn = (const float*)d_in[4];
  const float* w_proj = (const float*)d_in[5];
  const float* b_proj = (const float*)d_in[6];
  const float* thr    = (const float*)d_in[7];
  const float* leak   = (const float*)d_in[8];
  const float* steep  = (const float*)d_in[9];
  const float* ln2_w  = (const float*)d_in[10];
  const float* ln2_b  = (const float*)d_in[11];
  const float* w_fc   = (const float*)d_in[12];
  const float* b_fc   = (const float*)d_in[13];
  const float* w_mlp  = (const float*)d_in[14];
  const float* b_mlp  = (const float*)d_in[15];

  char* ws = (char*)d_ws;
  bf16_t* q    = (bf16_t*)(ws + 0);          //  8 MB
  bf16_t* k    = (bf16_t*)(ws + 8388608);    //  8 MB
  bf16_t* v    = (bf16_t*)(ws + 16777216);   //  8 MB (dead after transpose_v)
  bf16_t* vT   = (bf16_t*)(ws + 25165824);   //  8 MB
  bf16_t* gbuf = (bf16_t*)(ws + 0);          // 32 MB, aliases q/k/v/vT (dead)
  bf16_t* hbuf = (bf16_t*)(ws + 33554432);   //  8 MB, h -> Y -> h2
  float*  x2   = (float*) (ws + 41943040);   // 16 MB
  bf16_t* wT_attn = (bf16_t*)(ws + 58720256); // 6 MB
  bf16_t* wT_proj = (bf16_t*)(ws + 65011712); // 2 MB
  bf16_t* wT_fc   = (bf16_t*)(ws + 67108864); // 8 MB
  bf16_t* wT_mlp  = (bf16_t*)(ws + 75497472); // 8 MB -> 80 MB total

  // attention scratch (aliases v-slot and x2-slot, both dead during attention)
  uint2* yaccA = (uint2*)(ws + 16777216);
  uint2* yaccB = (uint2*)(ws + 41943040);
  float* denP  = (float*)(ws + 52428800);
  float2* mzP  = (float2*)(ws + 53477376);

  // proj split-K partial (dead q slot)
  bf16_t* pp1 = (bf16_t*)(ws + 0);
  // mlp_proj split-K partials (dead hbuf / wT_attn+wT_proj / wT_fc slots)
  bf16_t* mp1 = (bf16_t*)(ws + 33554432);
  bf16_t* mp2 = (bf16_t*)(ws + 58720256);
  bf16_t* mp3 = (bf16_t*)(ws + 67108864);

  float* out = (float*)d_out;

  // fused LN1 + 4 weight transposes (1 launch instead of 5)
  prep<<<dim3(MROWS + 12288), dim3(256), 0, stream>>>(
      x, ln1_w, ln1_b, hbuf,
      w_attn, wT_attn, w_proj, wT_proj, w_fc, wT_fc, w_mlp, wT_mlp);

  // QKV: 256x128 tile, 3-buffer counted-vmcnt pipeline
  gemmP<0><<<dim3(384, 1, 1), dim3(512), 0, stream>>>(
      hbuf, wT_attn, b_attn, nullptr, q, k, v, 3072, 1024, 1024, 24);
  transpose_v<<<dim3(64, 2, 32), dim3(256), 0, stream>>>(v, vT);

  // split-K attention: 4-wave 64-row blocks (measured-good config)
  attn_p1<<<dim3(2560), dim3(256), 0, stream>>>(q, k, mzP);
  attn_p3<<<dim3(2560), dim3(256), 0, stream>>>(
      q, k, vT, mzP, hbuf, yaccA, yaccB, denP, thr, leak, steep);
  attn_p4<<<dim3(3072), dim3(256), 0, stream>>>(yaccA, yaccB, denP, hbuf);

  // attn projection, split-K 2: z0 -> raw fp32 in x2, z1 -> bf16 pp1
  gemm_sk<<<dim3(32, 8, 2), dim3(256), 0, stream>>>(
      hbuf, wT_proj, x2, pp1, nullptr, nullptr, MROWS, 1024, 512, 1024);

  // LN2 fused with proj combine
  ln2_fuse<<<dim3(MROWS), dim3(256), 0, stream>>>(
      x2, pp1, x, b_proj, ln2_w, ln2_b, x2, hbuf);

  // MLP fc + GELU: 256x128 tile pipeline
  gemmP<2><<<dim3(512, 1, 1), dim3(512), 0, stream>>>(
      hbuf, wT_fc, b_fc, nullptr, gbuf, nullptr, nullptr, 4096, 1024, 1024, 32);

  // MLP proj, split-K 4: z0 -> raw fp32 in out, z1-3 -> bf16 mp1..3
  gemm_sk<<<dim3(32, 8, 4), dim3(256), 0, stream>>>(
      gbuf, wT_mlp, out, mp1, mp2, mp3, MROWS, 1024, 1024, 4096);

  // final combine: out += mp1+mp2+mp3 + b_mlp + x2
  combine3<<<dim3(4096), dim3(256), 0, stream>>>(out, mp1, mp2, mp3, b_mlp, x2);
}

// Round 14
// 283.259 us; speedup vs baseline: 1.0923x; 1.0175x over previous
//
#include <hip/hip_runtime.h>
#include <hip/hip_bf16.h>
#include <math.h>

typedef __bf16 bf16_t;
typedef __bf16 bf16x8 __attribute__((ext_vector_type(8)));
typedef __bf16 bf16x4 __attribute__((ext_vector_type(4)));
typedef float  f32x4  __attribute__((ext_vector_type(4)));
typedef unsigned int u32;

static constexpr int C_    = 1024;
static constexpr int NH    = 16;
static constexpr int DH    = 64;
static constexpr int BB    = 2;
static constexpr int TT    = 2048;
static constexpr int MROWS = BB * TT;   // 4096
static constexpr float LOG2E = 1.4426950408889634f;

// ---------------- helpers ----------------------------------------------------
__device__ __forceinline__ void gload_lds16(const bf16_t* src, bf16_t* dst) {
  __builtin_amdgcn_global_load_lds(
      (const __attribute__((address_space(1))) u32*)(src),
      (__attribute__((address_space(3))) u32*)(dst),
      16, 0, 0);
}

__device__ __forceinline__ u32 cvt_pk_bf16(float a, float b) {
  u32 r;
  asm("v_cvt_pk_bf16_f32 %0, %1, %2" : "=v"(r) : "v"(a), "v"(b));
  return r;
}

__device__ __forceinline__ float fexp2(float x) {
#if __has_builtin(__builtin_amdgcn_exp2f)
  return __builtin_amdgcn_exp2f(x);
#else
  return exp2f(x);
#endif
}
__device__ __forceinline__ float frcp(float x) {
#if __has_builtin(__builtin_amdgcn_rcpf)
  return __builtin_amdgcn_rcpf(x);
#else
  return 1.0f / x;
#endif
}

// cumulative item index for strip-of-16 s and chunk c (pid scheme, P4)
__device__ __forceinline__ int sc_to_t(int s, int c) {
  if (s < 32)  return s;
  if (s < 64)  return 32 + (s - 32) * 2 + c;
  if (s < 96)  return 96 + (s - 64) * 3 + c;
  return 192 + (s - 96) * 4 + c;
}

// block item (64-row group) mapping: item in [0,80) -> (u in [0,32), c)
__device__ __forceinline__ void item64_to_uc(int item, int& u, int& c) {
  if (item < 8)       { u = item;               c = 0; }
  else if (item < 24) { int v = item - 8;  u = 8  + (v >> 1); c = v & 1; }
  else if (item < 48) { int v = item - 24; u = 16 + v / 3;    c = v - 3 * (v / 3); }
  else                { int v = item - 48; u = 24 + (v >> 2); c = v & 3; }
}

// ---------------- fused prep: LN1 (blocks 0..4095) + 4 weight transposes ----
__global__ __launch_bounds__(256) void prep(
    const float* __restrict__ x, const float* __restrict__ ln1_w,
    const float* __restrict__ ln1_b, bf16_t* __restrict__ hout,
    const float* __restrict__ w_attn, bf16_t* __restrict__ wT_attn,
    const float* __restrict__ w_proj, bf16_t* __restrict__ wT_proj,
    const float* __restrict__ w_fc,   bf16_t* __restrict__ wT_fc,
    const float* __restrict__ w_mlp,  bf16_t* __restrict__ wT_mlp)
{
  const int bid = blockIdx.x;
  const int tid = threadIdx.x;
  if (bid < MROWS) {
    const int row = bid;
    const float4 v = reinterpret_cast<const float4*>(x + (size_t)row * C_)[tid];
    float s  = v.x + v.y + v.z + v.w;
    float s2 = v.x*v.x + v.y*v.y + v.z*v.z + v.w*v.w;
#pragma unroll
    for (int m = 1; m < 64; m <<= 1) { s += __shfl_xor(s, m); s2 += __shfl_xor(s2, m); }
    __shared__ float red[8];
    const int wv = tid >> 6;
    if ((tid & 63) == 0) { red[wv] = s; red[4 + wv] = s2; }
    __syncthreads();
    s  = red[0] + red[1] + red[2] + red[3];
    s2 = red[4] + red[5] + red[6] + red[7];
    const float mu   = s * (1.0f / C_);
    const float rstd = rsqrtf(s2 * (1.0f / C_) - mu * mu + 1e-5f);
    const float4 wv4 = reinterpret_cast<const float4*>(ln1_w)[tid];
    const float4 bv4 = reinterpret_cast<const float4*>(ln1_b)[tid];
    bf16x4 o;
    o[0] = (bf16_t)((v.x - mu) * rstd * wv4.x + bv4.x);
    o[1] = (bf16_t)((v.y - mu) * rstd * wv4.y + bv4.y);
    o[2] = (bf16_t)((v.z - mu) * rstd * wv4.z + bv4.z);
    o[3] = (bf16_t)((v.w - mu) * rstd * wv4.w + bv4.w);
    *reinterpret_cast<bf16x4*>(hout + (size_t)row * C_ + tid * 4) = o;
    return;
  }
  int tb = bid - MROWS;
  const float* in; bf16_t* out; int K, N, nbx;
  if (tb < 3072)      { in = w_attn; out = wT_attn; K = 1024; N = 3072; nbx = 96; }
  else if (tb < 4096) { tb -= 3072; in = w_proj; out = wT_proj; K = 1024; N = 1024; nbx = 32; }
  else if (tb < 8192) { tb -= 4096; in = w_fc;   out = wT_fc;   K = 1024; N = 4096; nbx = 128; }
  else                { tb -= 8192; in = w_mlp;  out = wT_mlp;  K = 4096; N = 1024; nbx = 32; }
  const int n0 = (tb % nbx) * 32, k0 = (tb / nbx) * 32;
  __shared__ float tile[32][33];
  const int tx = tid & 31, ty = tid >> 5;
#pragma unroll
  for (int i = 0; i < 4; ++i)
    tile[ty + i * 8][tx] = in[(size_t)(k0 + ty + i * 8) * N + n0 + tx];
  __syncthreads();
#pragma unroll
  for (int i = 0; i < 4; ++i)
    out[(size_t)(n0 + ty + i * 8) * K + k0 + tx] = (bf16_t)tile[tx][ty + i * 8];
}

// ---------------- LN2 fused with proj split-K combine ------------------------
__global__ __launch_bounds__(256) void ln2_fuse(
    const float* __restrict__ p0, const bf16_t* __restrict__ p1,
    const float* __restrict__ xin, const float* __restrict__ pbias,
    const float* __restrict__ w, const float* __restrict__ b,
    float* __restrict__ x2out, bf16_t* __restrict__ out)
{
  const int row = blockIdx.x;
  const int tid = threadIdx.x;
  const size_t base = (size_t)row * C_ + tid * 4;
  const float4 v0 = *reinterpret_cast<const float4*>(p0 + base);
  const bf16x4 v1 = *reinterpret_cast<const bf16x4*>(p1 + base);
  const float4 xr = *reinterpret_cast<const float4*>(xin + base);
  const float4 pb = *reinterpret_cast<const float4*>(pbias + tid * 4);
  float4 v;
  v.x = v0.x + (float)v1[0] + pb.x + xr.x;
  v.y = v0.y + (float)v1[1] + pb.y + xr.y;
  v.z = v0.z + (float)v1[2] + pb.z + xr.z;
  v.w = v0.w + (float)v1[3] + pb.w + xr.w;
  *reinterpret_cast<float4*>(x2out + base) = v;

  float s  = v.x + v.y + v.z + v.w;
  float s2 = v.x*v.x + v.y*v.y + v.z*v.z + v.w*v.w;
#pragma unroll
  for (int m = 1; m < 64; m <<= 1) { s += __shfl_xor(s, m); s2 += __shfl_xor(s2, m); }
  __shared__ float red[8];
  const int wv = tid >> 6;
  if ((tid & 63) == 0) { red[wv] = s; red[4 + wv] = s2; }
  __syncthreads();
  s  = red[0] + red[1] + red[2] + red[3];
  s2 = red[4] + red[5] + red[6] + red[7];
  const float mu   = s * (1.0f / C_);
  const float rstd = rsqrtf(s2 * (1.0f / C_) - mu * mu + 1e-5f);
  const float4 wv4 = reinterpret_cast<const float4*>(w)[tid];
  const float4 bv4 = reinterpret_cast<const float4*>(b)[tid];
  bf16x4 o;
  o[0] = (bf16_t)((v.x - mu) * rstd * wv4.x + bv4.x);
  o[1] = (bf16_t)((v.y - mu) * rstd * wv4.y + bv4.y);
  o[2] = (bf16_t)((v.z - mu) * rstd * wv4.z + bv4.z);
  o[3] = (bf16_t)((v.w - mu) * rstd * wv4.w + bv4.w);
  *reinterpret_cast<bf16x4*>(out + base) = o;
}

// ---------------- combine for mlp_proj split-K -------------------------------
__global__ __launch_bounds__(256) void combine3(
    float* __restrict__ out, const bf16_t* __restrict__ p1,
    const bf16_t* __restrict__ p2, const bf16_t* __restrict__ p3,
    const float* __restrict__ bias, const float* __restrict__ resid)
{
  const size_t idx = ((size_t)blockIdx.x * 256 + threadIdx.x) * 4;
  float4 o = *reinterpret_cast<const float4*>(out + idx);
  const bf16x4 a = *reinterpret_cast<const bf16x4*>(p1 + idx);
  const bf16x4 b = *reinterpret_cast<const bf16x4*>(p2 + idx);
  const bf16x4 c = *reinterpret_cast<const bf16x4*>(p3 + idx);
  const float4 r = *reinterpret_cast<const float4*>(resid + idx);
  const int col = (int)(idx & (C_ - 1));
  const float4 bv = *reinterpret_cast<const float4*>(bias + col);
  o.x += (float)a[0] + (float)b[0] + (float)c[0] + bv.x + r.x;
  o.y += (float)a[1] + (float)b[1] + (float)c[1] + bv.y + r.y;
  o.z += (float)a[2] + (float)b[2] + (float)c[2] + bv.z + r.z;
  o.w += (float)a[3] + (float)b[3] + (float)c[3] + bv.w + r.w;
  *reinterpret_cast<float4*>(out + idx) = o;
}

// ---------------- V transpose: bf16 [BH][T][D] -> [BH][D][T] -----------------
__global__ __launch_bounds__(256) void transpose_v(
    const bf16_t* __restrict__ in, bf16_t* __restrict__ out)
{
  __shared__ bf16_t tile[32][33];
  const int bh = blockIdx.z;
  const bf16_t* src = in  + (size_t)bh * TT * DH;
  bf16_t*       dst = out + (size_t)bh * TT * DH;
  const int tx = threadIdx.x & 31, ty = threadIdx.x >> 5;
  const int t0 = blockIdx.x * 32, d0 = blockIdx.y * 32;
#pragma unroll
  for (int i = 0; i < 4; ++i)
    tile[ty + i * 8][tx] = src[(size_t)(t0 + ty + i * 8) * DH + d0 + tx];
  __syncthreads();
#pragma unroll
  for (int i = 0; i < 4; ++i)
    dst[(size_t)(d0 + ty + i * 8) * TT + t0 + tx] = tile[tx][ty + i * 8];
}

// ---------------- 256x128 GEMM (fc only), 3-buffer LDS, counted vmcnt --------
// 2-D XCD rectangles: each XCD owns 8bm x 8bn, interior bn-fast so a
// residency round touches ~4 MB (fits per-XCD L2).
__global__ __launch_bounds__(512, 1) void gemmP(
    const bf16_t* __restrict__ A, const bf16_t* __restrict__ Bt,
    const float* __restrict__ bias, bf16_t* __restrict__ bout0,
    int N, int Kfull)
{
  __shared__ bf16_t As[3][256 * 64];   // 96 KB
  __shared__ bf16_t Bs[3][128 * 64];   // 48 KB
  const int tid  = threadIdx.x;
  const int wave = tid >> 6, lane = tid & 63;
  const int r = lane & 15, g = lane >> 4;
  const int wm = wave >> 2, wn = wave & 3;

  // 2-D XCD rectangle mapping (grid 512: 16 bm x 32 bn)
  const int xcd = blockIdx.x & 7;
  const int idx = blockIdx.x >> 3;                 // 0..63
  const int bm = ((xcd & 1) << 3) + (idx >> 3);    // 0..15
  const int bn = ((xcd >> 1) << 3) + (idx & 7);    // 0..31

  const bf16_t* Abase = A  + (size_t)bm * 256 * Kfull;
  const bf16_t* Bbase = Bt + (size_t)bn * 128 * Kfull;

  f32x4 acc[8][2] = {};

  auto STG_A = [&](int buf, int kt, int pass) {
    const int idx2 = pass * 512 + tid;
    const int rr = idx2 >> 3, cc = idx2 & 7, gs = cc ^ (rr & 7);
    gload_lds16(Abase + (size_t)rr * Kfull + kt + gs * 8, &As[buf][idx2 * 8]);
  };
  auto STG_B = [&](int buf, int kt, int pass) {
    const int idx2 = pass * 512 + tid;
    const int rr = idx2 >> 3, cc = idx2 & 7, gs = cc ^ (rr & 7);
    gload_lds16(Bbase + (size_t)rr * Kfull + kt + gs * 8, &Bs[buf][idx2 * 8]);
  };
  auto STAGE6 = [&](int buf, int kt) {
    STG_A(buf, kt, 0); STG_A(buf, kt, 1);
    STG_A(buf, kt, 2); STG_A(buf, kt, 3);
    STG_B(buf, kt, 0); STG_B(buf, kt, 1);
  };

  const int NT = Kfull >> 6;
  STAGE6(0, 0);
  STAGE6(1, 64);

  for (int t = 0; t < NT; ++t) {
    const int buf = t % 3;
    if (t + 1 < NT) asm volatile("s_waitcnt vmcnt(6)" ::: "memory");
    else            asm volatile("s_waitcnt vmcnt(0)" ::: "memory");
    __builtin_amdgcn_s_barrier();
    asm volatile("" ::: "memory");

    const bool pre = (t + 2 < NT);
    const int kn   = (t + 2) << 6;
    const int bnx  = (t + 2) % 3;

    bf16x8 bfr[2][2];
#pragma unroll
    for (int s2 = 0; s2 < 2; ++s2)
#pragma unroll
      for (int ni = 0; ni < 2; ++ni) {
        const int rr = wn * 32 + ni * 16 + r;
        bfr[s2][ni] = *reinterpret_cast<const bf16x8*>(
            &Bs[buf][rr * 64 + (((s2 << 2) | g) ^ (rr & 7)) * 8]);
      }
#pragma unroll
    for (int mh = 0; mh < 2; ++mh) {
      bf16x8 af[2][4];
#pragma unroll
      for (int s2 = 0; s2 < 2; ++s2)
#pragma unroll
        for (int mi = 0; mi < 4; ++mi) {
          const int rr = wm * 128 + (mh * 4 + mi) * 16 + r;
          af[s2][mi] = *reinterpret_cast<const bf16x8*>(
              &As[buf][rr * 64 + (((s2 << 2) | g) ^ (rr & 7)) * 8]);
        }
      if (pre) {
        if (mh == 0) { STG_A(bnx, kn, 0); STG_A(bnx, kn, 1); STG_A(bnx, kn, 2); }
        else         { STG_A(bnx, kn, 3); STG_B(bnx, kn, 0); STG_B(bnx, kn, 1); }
      }
      __builtin_amdgcn_s_setprio(1);
#pragma unroll
      for (int s2 = 0; s2 < 2; ++s2)
#pragma unroll
        for (int mi = 0; mi < 4; ++mi)
#pragma unroll
          for (int ni = 0; ni < 2; ++ni)
            acc[mh * 4 + mi][ni] = __builtin_amdgcn_mfma_f32_16x16x32_bf16(
                af[s2][mi], bfr[s2][ni], acc[mh * 4 + mi][ni], 0, 0, 0);
      __builtin_amdgcn_s_setprio(0);
    }
  }

#pragma unroll
  for (int mi = 0; mi < 8; ++mi) {
#pragma unroll
    for (int ni = 0; ni < 2; ++ni) {
      const int grow0 = bm * 256 + wm * 128 + mi * 16 + g * 4;
      const int gcol  = bn * 128 + wn * 32 + ni * 16 + r;
      const float bv = bias[gcol];
#pragma unroll
      for (int i = 0; i < 4; ++i) {
        const int grow = grow0 + i;
        const float v = acc[mi][ni][i] + bv;
        const float gl = 0.5f * v * (1.0f + erff(v * 0.70710678118654752f));
        bout0[(size_t)grow * N + gcol] = (bf16_t)gl;
      }
    }
  }
}

// ---------------- 128x128 GEMM: EPI 0 = qkv scatter, EPI 3 = split-K ---------
template<int EPI>
__global__ __launch_bounds__(256) void gemm_sk(
    const bf16_t* __restrict__ A, const bf16_t* __restrict__ Bt,
    const float* __restrict__ bias, float* __restrict__ fout,
    bf16_t* __restrict__ bout0, bf16_t* __restrict__ bout1,
    bf16_t* __restrict__ bout2, int M, int N, int Kc, int Kfull)
{
  constexpr int BM = 128, BN = 128, BK = 64;
  __shared__ bf16_t As[BM * BK];
  __shared__ bf16_t Bs[BN * BK];
  const int tid  = threadIdx.x;
  const int wave = tid >> 6, lane = tid & 63;
  const int r = lane & 15, g = lane >> 4;
  const int wm = wave >> 1, wn = wave & 1;
  const int bm = blockIdx.x, bn = blockIdx.y;
  const int z  = blockIdx.z;
  const int kstart = z * Kc;

  const bf16_t* Abase = A  + (size_t)bm * BM * Kfull;
  const bf16_t* Bbase = Bt + (size_t)bn * BN * Kfull;

  f32x4 acc[4][4] = {};

  for (int kt = kstart; kt < kstart + Kc; kt += BK) {
#pragma unroll
    for (int it = 0; it < 4; ++it) {
      const int c0 = it * 256 + wave * 64;
      const int idx = c0 + lane;
      const int rr = idx >> 3, cc = idx & 7;
      const int gs = cc ^ (rr & 7);
      gload_lds16(Abase + (size_t)rr * Kfull + kt + gs * 8, As + c0 * 8);
    }
#pragma unroll
    for (int it = 0; it < 4; ++it) {
      const int c0 = it * 256 + wave * 64;
      const int idx = c0 + lane;
      const int rr = idx >> 3, cc = idx & 7;
      const int gs = cc ^ (rr & 7);
      gload_lds16(Bbase + (size_t)rr * Kfull + kt + gs * 8, Bs + c0 * 8);
    }
    asm volatile("s_waitcnt vmcnt(0)" ::: "memory");
    __syncthreads();
#pragma unroll
    for (int s = 0; s < 2; ++s) {
      bf16x8 af[4], bfr[4];
#pragma unroll
      for (int mi = 0; mi < 4; ++mi) {
        const int rr = wm * 64 + mi * 16 + r;
        const int ch = (s * 4 + g) ^ (rr & 7);
        af[mi] = *reinterpret_cast<const bf16x8*>(&As[rr * BK + ch * 8]);
      }
#pragma unroll
      for (int ni = 0; ni < 4; ++ni) {
        const int rr = wn * 64 + ni * 16 + r;
        const int ch = (s * 4 + g) ^ (rr & 7);
        bfr[ni] = *reinterpret_cast<const bf16x8*>(&Bs[rr * BK + ch * 8]);
      }
#pragma unroll
      for (int mi = 0; mi < 4; ++mi)
#pragma unroll
        for (int ni = 0; ni < 4; ++ni)
          acc[mi][ni] = __builtin_amdgcn_mfma_f32_16x16x32_bf16(
              af[mi], bfr[ni], acc[mi][ni], 0, 0, 0);
    }
    __syncthreads();
  }

#pragma unroll
  for (int mi = 0; mi < 4; ++mi) {
#pragma unroll
    for (int ni = 0; ni < 4; ++ni) {
      const int grow0 = bm * BM + wm * 64 + mi * 16 + g * 4;
      const int gcol  = bn * BN + wn * 64 + ni * 16 + r;
      const float bv = (EPI == 0) ? bias[gcol] : 0.f;
#pragma unroll
      for (int i = 0; i < 4; ++i) {
        const int grow = grow0 + i;
        const float v = acc[mi][ni][i] + bv;
        if constexpr (EPI == 0) {
          const int which = gcol >> 10;
          const int c0 = gcol & 1023;
          const int hh = c0 >> 6, dd = c0 & 63;
          const int bb = grow >> 11, tt = grow & 2047;
          bf16_t* dst = (which == 0) ? bout0 : (which == 1) ? bout1 : bout2;
          dst[((size_t)(bb * NH + hh) * TT + tt) * DH + dd] = (bf16_t)v;
        } else {
          const size_t o = (size_t)grow * N + gcol;
          if (z == 0) fout[o] = v;
          else {
            bf16_t* pb = (z == 1) ? bout0 : (z == 2) ? bout1 : bout2;
            pb[o] = (bf16_t)v;
          }
        }
      }
    }
  }
}

// ====== split-K attention, 4-wave 64-row blocks, LDS-staged K/V =============

// ---- P1: partial (m, z) per (16-row strip, chunk) ---------------------------
__global__ __launch_bounds__(256, 4) void attn_p1(
    const bf16_t* __restrict__ Q, const bf16_t* __restrict__ Km,
    float2* __restrict__ mzP)
{
  __shared__ bf16_t Ks[2][64 * 64];
  const int tid = threadIdx.x;
  const int w = tid >> 6, lane = tid & 63;
  const int r = lane & 15, g = lane >> 4;
  const int bid = blockIdx.x;
  const int bh  = (bid & 7) * 4 + ((bid >> 3) & 3);
  int u, c; item64_to_uc(bid >> 5, u, c);
  const int cmax = u >> 3;
  const bool diag = (c == cmax);
  const int nt = diag ? (u & 7) + 1 : 8;
  const int s = 4 * u + w;
  const int row0 = u * 64 + w * 16;
  const int qrow = row0 + r;

  const bf16_t* Qh = Q  + (size_t)bh * TT * DH;
  const bf16_t* Kh = Km + (size_t)bh * TT * DH;
  const float SCL = 0.125f * LOG2E;

  bf16x8 qf[2];
#pragma unroll
  for (int s2 = 0; s2 < 2; ++s2) {
    bf16x8 t = *reinterpret_cast<const bf16x8*>(Qh + (size_t)qrow * DH + s2 * 32 + g * 8);
#pragma unroll
    for (int i = 0; i < 8; ++i) t[i] = (bf16_t)((float)t[i] * SCL);
    qf[s2] = t;
  }

  auto STAGEK = [&](int b, int t8) {
#pragma unroll
    for (int it = 0; it < 2; ++it) {
      const int idx = it * 256 + tid;
      const int rr = idx >> 3, cc = idx & 7, gs = cc ^ (rr & 7);
      gload_lds16(Kh + (size_t)(c * 512 + t8 * 64 + rr) * DH + gs * 8, &Ks[b][idx * 8]);
    }
  };

  float runM = -1e30f, runZ = 0.f;
  STAGEK(0, 0);
  for (int t8 = 0; t8 < nt; ++t8) {
    const int b = t8 & 1;
    asm volatile("s_waitcnt vmcnt(0)" ::: "memory");
    __syncthreads();
    if (t8 + 1 < nt) STAGEK(b ^ 1, t8 + 1);
    f32x4 sfT[4] = {};
#pragma unroll
    for (int s2 = 0; s2 < 2; ++s2) {
      bf16x8 kf[4];
#pragma unroll
      for (int ni = 0; ni < 4; ++ni)
        kf[ni] = *reinterpret_cast<const bf16x8*>(
            &Ks[b][(ni * 16 + r) * 64 + (((s2 << 2) | g) ^ (r & 7)) * 8]);
#pragma unroll
      for (int ni = 0; ni < 4; ++ni)
        sfT[ni] = __builtin_amdgcn_mfma_f32_16x16x32_bf16(kf[ni], qf[s2], sfT[ni], 0, 0, 0);
    }
    const bool dm = diag && (t8 == nt - 1);
    const int kbase = c * 512 + t8 * 64;
    float xv[16];
#pragma unroll
    for (int ni = 0; ni < 4; ++ni)
#pragma unroll
      for (int j = 0; j < 4; ++j) {
        float x = sfT[ni][j];
        if (dm) {
          const int kcol = kbase + ni * 16 + g * 4 + j;
          if (kcol > qrow) x = -1e30f;
        }
        xv[ni * 4 + j] = x;
      }
    float nm = runM;
#pragma unroll
    for (int e = 0; e < 16; ++e) nm = fmaxf(nm, xv[e]);
    float z = runZ * fexp2(runM - nm);
#pragma unroll
    for (int e = 0; e < 16; ++e) z += fexp2(xv[e] - nm);
    runM = nm; runZ = z;
  }
#pragma unroll
  for (int msk = 16; msk < 64; msk <<= 1) {
    const float om = __shfl_xor(runM, msk), oz = __shfl_xor(runZ, msk);
    const float nm = fmaxf(runM, om);
    runZ = runZ * fexp2(runM - nm) + oz * fexp2(om - nm);
    runM = nm;
  }
  if (lane < 16)
    mzP[((size_t)(bh * 128 + s) * 4 + c) * 16 + r] = make_float2(runM, runZ);
}

// ---- P3: gated partial yacc/den per chunk -----------------------------------
__global__ __launch_bounds__(256, 4) void attn_p3(
    const bf16_t* __restrict__ Q, const bf16_t* __restrict__ Km,
    const bf16_t* __restrict__ Vt, const float2* __restrict__ mzP,
    bf16_t* __restrict__ Y, uint2* __restrict__ yaccA,
    uint2* __restrict__ yaccB, float* __restrict__ denP,
    const float* __restrict__ thrp, const float* __restrict__ leakp,
    const float* __restrict__ steepp)
{
  __shared__ bf16_t Ks[2][64 * 64];
  __shared__ bf16_t Vs[2][64 * 64];
  __shared__ __align__(16) u32 Ms[4][512];

  const int tid = threadIdx.x;
  const int w = tid >> 6, lane = tid & 63;
  const int r = lane & 15, g = lane >> 4;
  const int bid = blockIdx.x;
  const int bh  = (bid & 7) * 4 + ((bid >> 3) & 3);
  int u, c; item64_to_uc(bid >> 5, u, c);
  const int cmax = u >> 3;
  const bool diag = (c == cmax);
  const int nt = diag ? (u & 7) + 1 : 8;
  const int nch = cmax + 1;
  const int s = 4 * u + w;
  const int row0 = u * 64 + w * 16;
  const int qrow = row0 + r;
  const int hh = bh & (NH - 1), bb = bh >> 4;

  const bf16_t* Qh  = Q  + (size_t)bh * TT * DH;
  const bf16_t* Kh  = Km + (size_t)bh * TT * DH;
  const bf16_t* Vth = Vt + (size_t)bh * TT * DH;

  const float lk  = 1.0f / (1.0f + expf(-leakp[hh]));
  const float ilk = 1.0f - lk;
  const float st  = log1pf(expf(steepp[hh]));
  const float Lst = LOG2E * st;
  const float A0  = Lst * (fabsf(thrp[hh]) * 0.1f);

  float M = -1e30f, Z = 0.f;
  for (int c2 = 0; c2 < nch; ++c2) {
    const float2 mz = mzP[((size_t)(bh * 128 + s) * 4 + c2) * 16 + r];
    const float nm = fmaxf(M, mz.x);
    Z = Z * fexp2(M - nm) + mz.y * fexp2(mz.x - nm);
    M = nm;
  }
  const float rcpZ = frcp(Z);

  const float SCL = 0.125f * LOG2E;
  bf16x8 qf[2];
#pragma unroll
  for (int s2 = 0; s2 < 2; ++s2) {
    bf16x8 t = *reinterpret_cast<const bf16x8*>(Qh + (size_t)qrow * DH + s2 * 32 + g * 8);
#pragma unroll
    for (int i = 0; i < 8; ++i) t[i] = (bf16_t)((float)t[i] * SCL);
    qf[s2] = t;
  }
  bf16x8 ones;
#pragma unroll
  for (int i = 0; i < 8; ++i) ones[i] = (bf16_t)1.0f;

  uint2* MsU2 = reinterpret_cast<uint2*>(&Ms[w][0]);
  uint4* MsU4 = reinterpret_cast<uint4*>(&Ms[w][0]);

  auto STAGE = [&](int b, int t8) {
    const int kbase = c * 512 + t8 * 64;
#pragma unroll
    for (int it = 0; it < 2; ++it) {
      const int idx = it * 256 + tid;
      const int rr = idx >> 3, cc = idx & 7, gs = cc ^ (rr & 7);
      gload_lds16(Kh + (size_t)(kbase + rr) * DH + gs * 8, &Ks[b][idx * 8]);
      gload_lds16(Vth + (size_t)rr * TT + kbase + gs * 8, &Vs[b][idx * 8]);
    }
  };

  f32x4 yacc[4] = {};
  f32x4 dacc = {};

  STAGE(0, 0);
  for (int t8 = 0; t8 < nt; ++t8) {
    const int b = t8 & 1;
    asm volatile("s_waitcnt vmcnt(0)" ::: "memory");
    __syncthreads();
    if (t8 + 1 < nt) STAGE(b ^ 1, t8 + 1);
    const int kbase = c * 512 + t8 * 64;
    f32x4 sfT[4] = {};
#pragma unroll
    for (int s2 = 0; s2 < 2; ++s2) {
      bf16x8 kf[4];
#pragma unroll
      for (int ni = 0; ni < 4; ++ni)
        kf[ni] = *reinterpret_cast<const bf16x8*>(
            &Ks[b][(ni * 16 + r) * 64 + (((s2 << 2) | g) ^ (r & 7)) * 8]);
#pragma unroll
      for (int ni = 0; ni < 4; ++ni)
        sfT[ni] = __builtin_amdgcn_mfma_f32_16x16x32_bf16(kf[ni], qf[s2], sfT[ni], 0, 0, 0);
    }
    const bool dm = diag && (t8 == nt - 1);
#pragma unroll
    for (int ni = 0; ni < 4; ++ni) {
      float mv[4];
#pragma unroll
      for (int j = 0; j < 4; ++j) {
        float x = sfT[ni][j];
        if (dm) {
          const int kcol = kbase + ni * 16 + g * 4 + j;
          if (kcol > qrow) x = -1e30f;
        }
        const float p    = fexp2(x - M) * rcpZ;
        const float fire = frcp(1.0f + fexp2(A0 - Lst * p));
        mv[j] = p * fmaf(ilk, fire, lk);
      }
      MsU2[r * 16 + ((4 * ni + g) ^ ((r & 7) << 1))] =
          make_uint2(cvt_pk_bf16(mv[0], mv[1]), cvt_pk_bf16(mv[2], mv[3]));
    }
#pragma unroll
    for (int s2 = 0; s2 < 2; ++s2) {
      const uint4 aw = MsU4[r * 8 + ((s2 * 4 + g) ^ (r & 7))];
      const bf16x8 af = __builtin_bit_cast(bf16x8, aw);
      bf16x8 vf[4];
#pragma unroll
      for (int ni = 0; ni < 4; ++ni)
        vf[ni] = *reinterpret_cast<const bf16x8*>(
            &Vs[b][(ni * 16 + r) * 64 + (((s2 << 2) | g) ^ (r & 7)) * 8]);
#pragma unroll
      for (int ni = 0; ni < 4; ++ni)
        yacc[ni] = __builtin_amdgcn_mfma_f32_16x16x32_bf16(af, vf[ni], yacc[ni], 0, 0, 0);
      dacc = __builtin_amdgcn_mfma_f32_16x16x32_bf16(af, ones, dacc, 0, 0, 0);
    }
  }

  if (nch == 1) {
#pragma unroll
    for (int j = 0; j < 4; ++j) {
      const float rd = frcp(dacc[j] + 1e-8f);
      const int t = row0 + g * 4 + j;
#pragma unroll
      for (int ni = 0; ni < 4; ++ni)
        Y[((size_t)(bb * TT + t)) * C_ + hh * DH + ni * 16 + r] =
            (bf16_t)(yacc[ni][j] * rd);
    }
  } else {
    const int pid = bh * 288 + (sc_to_t(s, c) - 32);
    uint2* pb = (pid < 4096) ? (yaccA + (size_t)pid * 256)
                             : (yaccB + (size_t)(pid - 4096) * 256);
#pragma unroll
    for (int ni = 0; ni < 4; ++ni)
      pb[ni * 64 + lane] =
          make_uint2(cvt_pk_bf16(yacc[ni][0], yacc[ni][1]),
                     cvt_pk_bf16(yacc[ni][2], yacc[ni][3]));
    if (r == 0)
      *reinterpret_cast<float4*>(&denP[(size_t)pid * 16 + g * 4]) =
          make_float4(dacc[0], dacc[1], dacc[2], dacc[3]);
  }
}

// ---- P4: combine chunk partials for strips >= 32 ----------------------------
__global__ __launch_bounds__(256) void attn_p4(
    const uint2* __restrict__ yaccA, const uint2* __restrict__ yaccB,
    const float* __restrict__ denP, bf16_t* __restrict__ Y)
{
  const int bid = blockIdx.x;
  const int bh  = bid / 96;
  const int s   = 32 + (bid - bh * 96);
  const int nch = (s >> 5) + 1;
  const int hh = bh & (NH - 1), bb = bh >> 4;

  const int tid = threadIdx.x;
  const int w = tid >> 6, lane = tid & 63;
  const int r = lane & 15, g = lane >> 4;

  float acc[4] = {};
  float den[4] = {};
  for (int c = 0; c < nch; ++c) {
    const int pid = bh * 288 + (sc_to_t(s, c) - 32);
    const uint2* pb = (pid < 4096) ? (yaccA + (size_t)pid * 256)
                                   : (yaccB + (size_t)(pid - 4096) * 256);
    const uint2 u = pb[w * 64 + lane];
    acc[0] += __builtin_bit_cast(float, (u.x & 0xFFFFu) << 16);
    acc[1] += __builtin_bit_cast(float, (u.x & 0xFFFF0000u));
    acc[2] += __builtin_bit_cast(float, (u.y & 0xFFFFu) << 16);
    acc[3] += __builtin_bit_cast(float, (u.y & 0xFFFF0000u));
    const float4 d4 = *reinterpret_cast<const float4*>(&denP[(size_t)pid * 16 + g * 4]);
    den[0] += d4.x; den[1] += d4.y; den[2] += d4.z; den[3] += d4.w;
  }
#pragma unroll
  for (int j = 0; j < 4; ++j) {
    const float rd = 1.0f / (den[j] + 1e-8f);
    const int t = s * 16 + g * 4 + j;
    Y[((size_t)(bb * TT + t)) * C_ + hh * DH + w * 16 + r] = (bf16_t)(acc[j] * rd);
  }
}

// ---------------------------------------------------------------------------
extern "C" void kernel_launch(void* const* d_in, const int* in_sizes, int n_in,
                              void* d_out, int out_size, void* d_ws, size_t ws_size,
                              hipStream_t stream)
{
  const float* x      = (const float*)d_in[0];
  const float* ln1_w  = (const float*)d_in[1];
  const float* ln1_b  = (const float*)d_in[2];
  const float* w_attn = (const float*)d_in[3];
  const float* b_attn = (const float*)d_in[4];
  const float* w_proj = (const float*)d_in[5];
  const float* b_proj = (const float*)d_in[6];
  const float* thr    = (const float*)d_in[7];
  const float* leak   = (const float*)d_in[8];
  const float* steep  = (const float*)d_in[9];
  const float* ln2_w  = (const float*)d_in[10];
  const float* ln2_b  = (const float*)d_in[11];
  const float* w_fc   = (const float*)d_in[12];
  const float* b_fc   = (const float*)d_in[13];
  const float* w_mlp  = (const float*)d_in[14];
  const float* b_mlp  = (const float*)d_in[15];

  char* ws = (char*)d_ws;
  bf16_t* q    = (bf16_t*)(ws + 0);          //  8 MB
  bf16_t* k    = (bf16_t*)(ws + 8388608);    //  8 MB
  bf16_t* v    = (bf16_t*)(ws + 16777216);   //  8 MB (dead after transpose_v)
  bf16_t* vT   = (bf16_t*)(ws + 25165824);   //  8 MB
  bf16_t* gbuf = (bf16_t*)(ws + 0);          // 32 MB, aliases q/k/v/vT (dead)
  bf16_t* hbuf = (bf16_t*)(ws + 33554432);   //  8 MB, h -> Y -> h2
  float*  x2   = (float*) (ws + 41943040);   // 16 MB
  bf16_t* wT_attn = (bf16_t*)(ws + 58720256); // 6 MB
  bf16_t* wT_proj = (bf16_t*)(ws + 65011712); // 2 MB
  bf16_t* wT_fc   = (bf16_t*)(ws + 67108864); // 8 MB
  bf16_t* wT_mlp  = (bf16_t*)(ws + 75497472); // 8 MB -> 80 MB total

  // attention scratch (aliases v-slot and x2-slot, both dead during attention)
  uint2* yaccA = (uint2*)(ws + 16777216);
  uint2* yaccB = (uint2*)(ws + 41943040);
  float* denP  = (float*)(ws + 52428800);
  float2* mzP  = (float2*)(ws + 53477376);

  // proj split-K partial (dead q slot)
  bf16_t* pp1 = (bf16_t*)(ws + 0);
  // mlp_proj split-K partials (dead hbuf / wT_attn+wT_proj / wT_fc slots)
  bf16_t* mp1 = (bf16_t*)(ws + 33554432);
  bf16_t* mp2 = (bf16_t*)(ws + 58720256);
  bf16_t* mp3 = (bf16_t*)(ws + 67108864);

  float* out = (float*)d_out;

  // fused LN1 + 4 weight transposes (1 launch)
  prep<<<dim3(MROWS + 12288), dim3(256), 0, stream>>>(
      x, ln1_w, ln1_b, hbuf,
      w_attn, wT_attn, w_proj, wT_proj, w_fc, wT_fc, w_mlp, wT_mlp);

  // QKV: 128^2 tile, grid 768 = 3 blocks/CU fully resident (no tail round)
  gemm_sk<0><<<dim3(32, 24, 1), dim3(256), 0, stream>>>(
      hbuf, wT_attn, b_attn, nullptr, q, k, v, MROWS, 3072, 1024, 1024);
  transpose_v<<<dim3(64, 2, 32), dim3(256), 0, stream>>>(v, vT);

  // split-K attention: 4-wave 64-row blocks
  attn_p1<<<dim3(2560), dim3(256), 0, stream>>>(q, k, mzP);
  attn_p3<<<dim3(2560), dim3(256), 0, stream>>>(
      q, k, vT, mzP, hbuf, yaccA, yaccB, denP, thr, leak, steep);
  attn_p4<<<dim3(3072), dim3(256), 0, stream>>>(yaccA, yaccB, denP, hbuf);

  // attn projection, split-K 2: z0 -> raw fp32 in x2, z1 -> bf16 pp1
  gemm_sk<3><<<dim3(32, 8, 2), dim3(256), 0, stream>>>(
      hbuf, wT_proj, nullptr, x2, pp1, nullptr, nullptr, MROWS, 1024, 512, 1024);

  // LN2 fused with proj combine
  ln2_fuse<<<dim3(MROWS), dim3(256), 0, stream>>>(
      x2, pp1, x, b_proj, ln2_w, ln2_b, x2, hbuf);

  // MLP fc + GELU: 256x128 pipeline with 2-D XCD rectangles
  gemmP<<<dim3(512, 1, 1), dim3(512), 0, stream>>>(
      hbuf, wT_fc, b_fc, gbuf, 4096, 1024);

  // MLP proj, split-K 4: z0 -> raw fp32 in out, z1-3 -> bf16 mp1..3
  gemm_sk<3><<<dim3(32, 8, 4), dim3(256), 0, stream>>>(
      gbuf, wT_mlp, nullptr, out, mp1, mp2, mp3, MROWS, 1024, 1024, 4096);

  // final combine: out += mp1+mp2+mp3 + b_mlp + x2
  combine3<<<dim3(4096), dim3(256), 0, stream>>>(out, mp1, mp2, mp3, b_mlp, x2);
}

// Round 15
// 282.496 us; speedup vs baseline: 1.0953x; 1.0027x over previous
//
#include <hip/hip_runtime.h>
#include <hip/hip_bf16.h>
#include <math.h>

typedef __bf16 bf16_t;
typedef __bf16 bf16x8 __attribute__((ext_vector_type(8)));
typedef __bf16 bf16x4 __attribute__((ext_vector_type(4)));
typedef float  f32x4  __attribute__((ext_vector_type(4)));
typedef unsigned int u32;

static constexpr int C_    = 1024;
static constexpr int NH    = 16;
static constexpr int DH    = 64;
static constexpr int BB    = 2;
static constexpr int TT    = 2048;
static constexpr int MROWS = BB * TT;   // 4096
static constexpr float LOG2E = 1.4426950408889634f;

// ---------------- helpers ----------------------------------------------------
__device__ __forceinline__ void gload_lds16(const bf16_t* src, bf16_t* dst) {
  __builtin_amdgcn_global_load_lds(
      (const __attribute__((address_space(1))) u32*)(src),
      (__attribute__((address_space(3))) u32*)(dst),
      16, 0, 0);
}

__device__ __forceinline__ u32 cvt_pk_bf16(float a, float b) {
  u32 r;
  asm("v_cvt_pk_bf16_f32 %0, %1, %2" : "=v"(r) : "v"(a), "v"(b));
  return r;
}

__device__ __forceinline__ float fexp2(float x) {
#if __has_builtin(__builtin_amdgcn_exp2f)
  return __builtin_amdgcn_exp2f(x);
#else
  return exp2f(x);
#endif
}
__device__ __forceinline__ float frcp(float x) {
#if __has_builtin(__builtin_amdgcn_rcpf)
  return __builtin_amdgcn_rcpf(x);
#else
  return 1.0f / x;
#endif
}

// cumulative item index for strip-of-16 s and chunk c (pid scheme, P4)
__device__ __forceinline__ int sc_to_t(int s, int c) {
  if (s < 32)  return s;
  if (s < 64)  return 32 + (s - 32) * 2 + c;
  if (s < 96)  return 96 + (s - 64) * 3 + c;
  return 192 + (s - 96) * 4 + c;
}

// block item (64-row group) mapping: item in [0,80) -> (u in [0,32), c)
__device__ __forceinline__ void item64_to_uc(int item, int& u, int& c) {
  if (item < 8)       { u = item;               c = 0; }
  else if (item < 24) { int v = item - 8;  u = 8  + (v >> 1); c = v & 1; }
  else if (item < 48) { int v = item - 24; u = 16 + v / 3;    c = v - 3 * (v / 3); }
  else                { int v = item - 48; u = 24 + (v >> 2); c = v & 3; }
}

// ---------------- fused prep: LN1 (blocks 0..4095) + 4 weight transposes ----
__global__ __launch_bounds__(256) void prep(
    const float* __restrict__ x, const float* __restrict__ ln1_w,
    const float* __restrict__ ln1_b, bf16_t* __restrict__ hout,
    const float* __restrict__ w_attn, bf16_t* __restrict__ wT_attn,
    const float* __restrict__ w_proj, bf16_t* __restrict__ wT_proj,
    const float* __restrict__ w_fc,   bf16_t* __restrict__ wT_fc,
    const float* __restrict__ w_mlp,  bf16_t* __restrict__ wT_mlp)
{
  const int bid = blockIdx.x;
  const int tid = threadIdx.x;
  if (bid < MROWS) {
    const int row = bid;
    const float4 v = reinterpret_cast<const float4*>(x + (size_t)row * C_)[tid];
    float s  = v.x + v.y + v.z + v.w;
    float s2 = v.x*v.x + v.y*v.y + v.z*v.z + v.w*v.w;
#pragma unroll
    for (int m = 1; m < 64; m <<= 1) { s += __shfl_xor(s, m); s2 += __shfl_xor(s2, m); }
    __shared__ float red[8];
    const int wv = tid >> 6;
    if ((tid & 63) == 0) { red[wv] = s; red[4 + wv] = s2; }
    __syncthreads();
    s  = red[0] + red[1] + red[2] + red[3];
    s2 = red[4] + red[5] + red[6] + red[7];
    const float mu   = s * (1.0f / C_);
    const float rstd = rsqrtf(s2 * (1.0f / C_) - mu * mu + 1e-5f);
    const float4 wv4 = reinterpret_cast<const float4*>(ln1_w)[tid];
    const float4 bv4 = reinterpret_cast<const float4*>(ln1_b)[tid];
    bf16x4 o;
    o[0] = (bf16_t)((v.x - mu) * rstd * wv4.x + bv4.x);
    o[1] = (bf16_t)((v.y - mu) * rstd * wv4.y + bv4.y);
    o[2] = (bf16_t)((v.z - mu) * rstd * wv4.z + bv4.z);
    o[3] = (bf16_t)((v.w - mu) * rstd * wv4.w + bv4.w);
    *reinterpret_cast<bf16x4*>(hout + (size_t)row * C_ + tid * 4) = o;
    return;
  }
  int tb = bid - MROWS;
  const float* in; bf16_t* out; int K, N, nbx;
  if (tb < 3072)      { in = w_attn; out = wT_attn; K = 1024; N = 3072; nbx = 96; }
  else if (tb < 4096) { tb -= 3072; in = w_proj; out = wT_proj; K = 1024; N = 1024; nbx = 32; }
  else if (tb < 8192) { tb -= 4096; in = w_fc;   out = wT_fc;   K = 1024; N = 4096; nbx = 128; }
  else                { tb -= 8192; in = w_mlp;  out = wT_mlp;  K = 4096; N = 1024; nbx = 32; }
  const int n0 = (tb % nbx) * 32, k0 = (tb / nbx) * 32;
  __shared__ float tile[32][33];
  const int tx = tid & 31, ty = tid >> 5;
#pragma unroll
  for (int i = 0; i < 4; ++i)
    tile[ty + i * 8][tx] = in[(size_t)(k0 + ty + i * 8) * N + n0 + tx];
  __syncthreads();
#pragma unroll
  for (int i = 0; i < 4; ++i)
    out[(size_t)(n0 + ty + i * 8) * K + k0 + tx] = (bf16_t)tile[tx][ty + i * 8];
}

// ---------------- LN2 fused with proj split-K combine ------------------------
__global__ __launch_bounds__(256) void ln2_fuse(
    const float* __restrict__ p0, const bf16_t* __restrict__ p1,
    const float* __restrict__ xin, const float* __restrict__ pbias,
    const float* __restrict__ w, const float* __restrict__ b,
    float* __restrict__ x2out, bf16_t* __restrict__ out)
{
  const int row = blockIdx.x;
  const int tid = threadIdx.x;
  const size_t base = (size_t)row * C_ + tid * 4;
  const float4 v0 = *reinterpret_cast<const float4*>(p0 + base);
  const bf16x4 v1 = *reinterpret_cast<const bf16x4*>(p1 + base);
  const float4 xr = *reinterpret_cast<const float4*>(xin + base);
  const float4 pb = *reinterpret_cast<const float4*>(pbias + tid * 4);
  float4 v;
  v.x = v0.x + (float)v1[0] + pb.x + xr.x;
  v.y = v0.y + (float)v1[1] + pb.y + xr.y;
  v.z = v0.z + (float)v1[2] + pb.z + xr.z;
  v.w = v0.w + (float)v1[3] + pb.w + xr.w;
  *reinterpret_cast<float4*>(x2out + base) = v;

  float s  = v.x + v.y + v.z + v.w;
  float s2 = v.x*v.x + v.y*v.y + v.z*v.z + v.w*v.w;
#pragma unroll
  for (int m = 1; m < 64; m <<= 1) { s += __shfl_xor(s, m); s2 += __shfl_xor(s2, m); }
  __shared__ float red[8];
  const int wv = tid >> 6;
  if ((tid & 63) == 0) { red[wv] = s; red[4 + wv] = s2; }
  __syncthreads();
  s  = red[0] + red[1] + red[2] + red[3];
  s2 = red[4] + red[5] + red[6] + red[7];
  const float mu   = s * (1.0f / C_);
  const float rstd = rsqrtf(s2 * (1.0f / C_) - mu * mu + 1e-5f);
  const float4 wv4 = reinterpret_cast<const float4*>(w)[tid];
  const float4 bv4 = reinterpret_cast<const float4*>(b)[tid];
  bf16x4 o;
  o[0] = (bf16_t)((v.x - mu) * rstd * wv4.x + bv4.x);
  o[1] = (bf16_t)((v.y - mu) * rstd * wv4.y + bv4.y);
  o[2] = (bf16_t)((v.z - mu) * rstd * wv4.z + bv4.z);
  o[3] = (bf16_t)((v.w - mu) * rstd * wv4.w + bv4.w);
  *reinterpret_cast<bf16x4*>(out + base) = o;
}

// ---------------- combine for mlp_proj split-K -------------------------------
__global__ __launch_bounds__(256) void combine3(
    float* __restrict__ out, const bf16_t* __restrict__ p1,
    const bf16_t* __restrict__ p2, const bf16_t* __restrict__ p3,
    const float* __restrict__ bias, const float* __restrict__ resid)
{
  const size_t idx = ((size_t)blockIdx.x * 256 + threadIdx.x) * 4;
  float4 o = *reinterpret_cast<const float4*>(out + idx);
  const bf16x4 a = *reinterpret_cast<const bf16x4*>(p1 + idx);
  const bf16x4 b = *reinterpret_cast<const bf16x4*>(p2 + idx);
  const bf16x4 c = *reinterpret_cast<const bf16x4*>(p3 + idx);
  const float4 r = *reinterpret_cast<const float4*>(resid + idx);
  const int col = (int)(idx & (C_ - 1));
  const float4 bv = *reinterpret_cast<const float4*>(bias + col);
  o.x += (float)a[0] + (float)b[0] + (float)c[0] + bv.x + r.x;
  o.y += (float)a[1] + (float)b[1] + (float)c[1] + bv.y + r.y;
  o.z += (float)a[2] + (float)b[2] + (float)c[2] + bv.z + r.z;
  o.w += (float)a[3] + (float)b[3] + (float)c[3] + bv.w + r.w;
  *reinterpret_cast<float4*>(out + idx) = o;
}

// ---------------- 256x128 GEMM (fc only), 3-buffer LDS, counted vmcnt --------
__global__ __launch_bounds__(512, 1) void gemmP(
    const bf16_t* __restrict__ A, const bf16_t* __restrict__ Bt,
    const float* __restrict__ bias, bf16_t* __restrict__ bout0,
    int N, int Kfull)
{
  __shared__ bf16_t As[3][256 * 64];   // 96 KB
  __shared__ bf16_t Bs[3][128 * 64];   // 48 KB
  const int tid  = threadIdx.x;
  const int wave = tid >> 6, lane = tid & 63;
  const int r = lane & 15, g = lane >> 4;
  const int wm = wave >> 2, wn = wave & 3;

  // 2-D XCD rectangle mapping (grid 512: 16 bm x 32 bn)
  const int xcd = blockIdx.x & 7;
  const int idx = blockIdx.x >> 3;                 // 0..63
  const int bm = ((xcd & 1) << 3) + (idx >> 3);    // 0..15
  const int bn = ((xcd >> 1) << 3) + (idx & 7);    // 0..31

  const bf16_t* Abase = A  + (size_t)bm * 256 * Kfull;
  const bf16_t* Bbase = Bt + (size_t)bn * 128 * Kfull;

  f32x4 acc[8][2] = {};

  auto STG_A = [&](int buf, int kt, int pass) {
    const int idx2 = pass * 512 + tid;
    const int rr = idx2 >> 3, cc = idx2 & 7, gs = cc ^ (rr & 7);
    gload_lds16(Abase + (size_t)rr * Kfull + kt + gs * 8, &As[buf][idx2 * 8]);
  };
  auto STG_B = [&](int buf, int kt, int pass) {
    const int idx2 = pass * 512 + tid;
    const int rr = idx2 >> 3, cc = idx2 & 7, gs = cc ^ (rr & 7);
    gload_lds16(Bbase + (size_t)rr * Kfull + kt + gs * 8, &Bs[buf][idx2 * 8]);
  };
  auto STAGE6 = [&](int buf, int kt) {
    STG_A(buf, kt, 0); STG_A(buf, kt, 1);
    STG_A(buf, kt, 2); STG_A(buf, kt, 3);
    STG_B(buf, kt, 0); STG_B(buf, kt, 1);
  };

  const int NT = Kfull >> 6;
  STAGE6(0, 0);
  STAGE6(1, 64);

  for (int t = 0; t < NT; ++t) {
    const int buf = t % 3;
    if (t + 1 < NT) asm volatile("s_waitcnt vmcnt(6)" ::: "memory");
    else            asm volatile("s_waitcnt vmcnt(0)" ::: "memory");
    __builtin_amdgcn_s_barrier();
    asm volatile("" ::: "memory");

    const bool pre = (t + 2 < NT);
    const int kn   = (t + 2) << 6;
    const int bnx  = (t + 2) % 3;

    bf16x8 bfr[2][2];
#pragma unroll
    for (int s2 = 0; s2 < 2; ++s2)
#pragma unroll
      for (int ni = 0; ni < 2; ++ni) {
        const int rr = wn * 32 + ni * 16 + r;
        bfr[s2][ni] = *reinterpret_cast<const bf16x8*>(
            &Bs[buf][rr * 64 + (((s2 << 2) | g) ^ (rr & 7)) * 8]);
      }
#pragma unroll
    for (int mh = 0; mh < 2; ++mh) {
      bf16x8 af[2][4];
#pragma unroll
      for (int s2 = 0; s2 < 2; ++s2)
#pragma unroll
        for (int mi = 0; mi < 4; ++mi) {
          const int rr = wm * 128 + (mh * 4 + mi) * 16 + r;
          af[s2][mi] = *reinterpret_cast<const bf16x8*>(
              &As[buf][rr * 64 + (((s2 << 2) | g) ^ (rr & 7)) * 8]);
        }
      if (pre) {
        if (mh == 0) { STG_A(bnx, kn, 0); STG_A(bnx, kn, 1); STG_A(bnx, kn, 2); }
        else         { STG_A(bnx, kn, 3); STG_B(bnx, kn, 0); STG_B(bnx, kn, 1); }
      }
      __builtin_amdgcn_s_setprio(1);
#pragma unroll
      for (int s2 = 0; s2 < 2; ++s2)
#pragma unroll
        for (int mi = 0; mi < 4; ++mi)
#pragma unroll
          for (int ni = 0; ni < 2; ++ni)
            acc[mh * 4 + mi][ni] = __builtin_amdgcn_mfma_f32_16x16x32_bf16(
                af[s2][mi], bfr[s2][ni], acc[mh * 4 + mi][ni], 0, 0, 0);
      __builtin_amdgcn_s_setprio(0);
    }
  }

#pragma unroll
  for (int mi = 0; mi < 8; ++mi) {
#pragma unroll
    for (int ni = 0; ni < 2; ++ni) {
      const int grow0 = bm * 256 + wm * 128 + mi * 16 + g * 4;
      const int gcol  = bn * 128 + wn * 32 + ni * 16 + r;
      const float bv = bias[gcol];
#pragma unroll
      for (int i = 0; i < 4; ++i) {
        const int grow = grow0 + i;
        const float v = acc[mi][ni][i] + bv;
        const float gl = 0.5f * v * (1.0f + erff(v * 0.70710678118654752f));
        bout0[(size_t)grow * N + gcol] = (bf16_t)gl;
      }
    }
  }
}

// ---------------- 128x128 GEMM: EPI 0 = qkv scatter, EPI 3 = split-K ---------
template<int EPI>
__global__ __launch_bounds__(256) void gemm_sk(
    const bf16_t* __restrict__ A, const bf16_t* __restrict__ Bt,
    const float* __restrict__ bias, float* __restrict__ fout,
    bf16_t* __restrict__ bout0, bf16_t* __restrict__ bout1,
    bf16_t* __restrict__ bout2, int M, int N, int Kc, int Kfull)
{
  constexpr int BM = 128, BN = 128, BK = 64;
  __shared__ bf16_t As[BM * BK];
  __shared__ bf16_t Bs[BN * BK];
  const int tid  = threadIdx.x;
  const int wave = tid >> 6, lane = tid & 63;
  const int r = lane & 15, g = lane >> 4;
  const int wm = wave >> 1, wn = wave & 1;
  const int bm = blockIdx.x, bn = blockIdx.y;
  const int z  = blockIdx.z;
  const int kstart = z * Kc;

  const bf16_t* Abase = A  + (size_t)bm * BM * Kfull;
  const bf16_t* Bbase = Bt + (size_t)bn * BN * Kfull;

  f32x4 acc[4][4] = {};

  for (int kt = kstart; kt < kstart + Kc; kt += BK) {
#pragma unroll
    for (int it = 0; it < 4; ++it) {
      const int c0 = it * 256 + wave * 64;
      const int idx = c0 + lane;
      const int rr = idx >> 3, cc = idx & 7;
      const int gs = cc ^ (rr & 7);
      gload_lds16(Abase + (size_t)rr * Kfull + kt + gs * 8, As + c0 * 8);
    }
#pragma unroll
    for (int it = 0; it < 4; ++it) {
      const int c0 = it * 256 + wave * 64;
      const int idx = c0 + lane;
      const int rr = idx >> 3, cc = idx & 7;
      const int gs = cc ^ (rr & 7);
      gload_lds16(Bbase + (size_t)rr * Kfull + kt + gs * 8, Bs + c0 * 8);
    }
    asm volatile("s_waitcnt vmcnt(0)" ::: "memory");
    __syncthreads();
#pragma unroll
    for (int s = 0; s < 2; ++s) {
      bf16x8 af[4], bfr[4];
#pragma unroll
      for (int mi = 0; mi < 4; ++mi) {
        const int rr = wm * 64 + mi * 16 + r;
        const int ch = (s * 4 + g) ^ (rr & 7);
        af[mi] = *reinterpret_cast<const bf16x8*>(&As[rr * BK + ch * 8]);
      }
#pragma unroll
      for (int ni = 0; ni < 4; ++ni) {
        const int rr = wn * 64 + ni * 16 + r;
        const int ch = (s * 4 + g) ^ (rr & 7);
        bfr[ni] = *reinterpret_cast<const bf16x8*>(&Bs[rr * BK + ch * 8]);
      }
#pragma unroll
      for (int mi = 0; mi < 4; ++mi)
#pragma unroll
        for (int ni = 0; ni < 4; ++ni)
          acc[mi][ni] = __builtin_amdgcn_mfma_f32_16x16x32_bf16(
              af[mi], bfr[ni], acc[mi][ni], 0, 0, 0);
    }
    __syncthreads();
  }

#pragma unroll
  for (int mi = 0; mi < 4; ++mi) {
#pragma unroll
    for (int ni = 0; ni < 4; ++ni) {
      const int grow0 = bm * BM + wm * 64 + mi * 16 + g * 4;
      const int gcol  = bn * BN + wn * 64 + ni * 16 + r;
      const float bv = (EPI == 0) ? bias[gcol] : 0.f;
#pragma unroll
      for (int i = 0; i < 4; ++i) {
        const int grow = grow0 + i;
        const float v = acc[mi][ni][i] + bv;
        if constexpr (EPI == 0) {
          const int which = gcol >> 10;
          const int c0 = gcol & 1023;
          const int hh = c0 >> 6, dd = c0 & 63;
          const int bb = grow >> 11, tt = grow & 2047;
          bf16_t* dst = (which == 0) ? bout0 : (which == 1) ? bout1 : bout2;
          dst[((size_t)(bb * NH + hh) * TT + tt) * DH + dd] = (bf16_t)v;
        } else {
          const size_t o = (size_t)grow * N + gcol;
          if (z == 0) fout[o] = v;
          else {
            bf16_t* pb = (z == 1) ? bout0 : (z == 2) ? bout1 : bout2;
            pb[o] = (bf16_t)v;
          }
        }
      }
    }
  }
}

// ====== split-K attention, 4-wave 64-row blocks, LDS-staged K/V =============

// ---- P1 (+ fused V transpose): blocks [0,4096) transpose V->vT;
//      blocks [4096, 4096+2560) compute partial (m,z) per strip/chunk --------
__global__ __launch_bounds__(256, 4) void attn_p1t(
    const bf16_t* __restrict__ Q, const bf16_t* __restrict__ Km,
    const bf16_t* __restrict__ V, bf16_t* __restrict__ vT,
    float2* __restrict__ mzP)
{
  __shared__ bf16_t Ks[2][64 * 64];
  __shared__ bf16_t ttile[32][33];
  const int tid = threadIdx.x;

  if (blockIdx.x < 4096) {
    // ---- V transpose block: [BH][T][D] -> [BH][D][T]
    const int tb = blockIdx.x;
    const int bh = tb >> 7;
    const int rem = tb & 127;
    const int t0 = (rem & 63) * 32, d0 = (rem >> 6) * 32;
    const bf16_t* src = V  + (size_t)bh * TT * DH;
    bf16_t*       dst = vT + (size_t)bh * TT * DH;
    const int tx = tid & 31, ty = tid >> 5;
#pragma unroll
    for (int i = 0; i < 4; ++i)
      ttile[ty + i * 8][tx] = src[(size_t)(t0 + ty + i * 8) * DH + d0 + tx];
    __syncthreads();
#pragma unroll
    for (int i = 0; i < 4; ++i)
      dst[(size_t)(d0 + ty + i * 8) * TT + t0 + tx] = ttile[tx][ty + i * 8];
    return;
  }

  const int bid = blockIdx.x - 4096;
  const int w = tid >> 6, lane = tid & 63;
  const int r = lane & 15, g = lane >> 4;
  const int bh  = (bid & 7) * 4 + ((bid >> 3) & 3);
  int u, c; item64_to_uc(bid >> 5, u, c);
  const int cmax = u >> 3;
  const bool diag = (c == cmax);
  const int nt = diag ? (u & 7) + 1 : 8;
  const int s = 4 * u + w;
  const int row0 = u * 64 + w * 16;
  const int qrow = row0 + r;

  const bf16_t* Qh = Q  + (size_t)bh * TT * DH;
  const bf16_t* Kh = Km + (size_t)bh * TT * DH;
  const float SCL = 0.125f * LOG2E;

  bf16x8 qf[2];
#pragma unroll
  for (int s2 = 0; s2 < 2; ++s2) {
    bf16x8 t = *reinterpret_cast<const bf16x8*>(Qh + (size_t)qrow * DH + s2 * 32 + g * 8);
#pragma unroll
    for (int i = 0; i < 8; ++i) t[i] = (bf16_t)((float)t[i] * SCL);
    qf[s2] = t;
  }

  auto STAGEK = [&](int b, int t8) {
#pragma unroll
    for (int it = 0; it < 2; ++it) {
      const int idx = it * 256 + tid;
      const int rr = idx >> 3, cc = idx & 7, gs = cc ^ (rr & 7);
      gload_lds16(Kh + (size_t)(c * 512 + t8 * 64 + rr) * DH + gs * 8, &Ks[b][idx * 8]);
    }
  };

  float runM = -1e30f, runZ = 0.f;
  STAGEK(0, 0);
  for (int t8 = 0; t8 < nt; ++t8) {
    const int b = t8 & 1;
    asm volatile("s_waitcnt vmcnt(0)" ::: "memory");
    __syncthreads();
    if (t8 + 1 < nt) STAGEK(b ^ 1, t8 + 1);
    f32x4 sfT[4] = {};
#pragma unroll
    for (int s2 = 0; s2 < 2; ++s2) {
      bf16x8 kf[4];
#pragma unroll
      for (int ni = 0; ni < 4; ++ni)
        kf[ni] = *reinterpret_cast<const bf16x8*>(
            &Ks[b][(ni * 16 + r) * 64 + (((s2 << 2) | g) ^ (r & 7)) * 8]);
#pragma unroll
      for (int ni = 0; ni < 4; ++ni)
        sfT[ni] = __builtin_amdgcn_mfma_f32_16x16x32_bf16(kf[ni], qf[s2], sfT[ni], 0, 0, 0);
    }
    const bool dm = diag && (t8 == nt - 1);
    const int kbase = c * 512 + t8 * 64;
    float xv[16];
#pragma unroll
    for (int ni = 0; ni < 4; ++ni)
#pragma unroll
      for (int j = 0; j < 4; ++j) {
        float x = sfT[ni][j];
        if (dm) {
          const int kcol = kbase + ni * 16 + g * 4 + j;
          if (kcol > qrow) x = -1e30f;
        }
        xv[ni * 4 + j] = x;
      }
    float nm = runM;
#pragma unroll
    for (int e = 0; e < 16; ++e) nm = fmaxf(nm, xv[e]);
    float z = runZ * fexp2(runM - nm);
#pragma unroll
    for (int e = 0; e < 16; ++e) z += fexp2(xv[e] - nm);
    runM = nm; runZ = z;
  }
#pragma unroll
  for (int msk = 16; msk < 64; msk <<= 1) {
    const float om = __shfl_xor(runM, msk), oz = __shfl_xor(runZ, msk);
    const float nm = fmaxf(runM, om);
    runZ = runZ * fexp2(runM - nm) + oz * fexp2(om - nm);
    runM = nm;
  }
  if (lane < 16)
    mzP[((size_t)(bh * 128 + s) * 4 + c) * 16 + r] = make_float2(runM, runZ);
}

// ---- P3: gated partial yacc/den per chunk -----------------------------------
__global__ __launch_bounds__(256, 4) void attn_p3(
    const bf16_t* __restrict__ Q, const bf16_t* __restrict__ Km,
    const bf16_t* __restrict__ Vt, const float2* __restrict__ mzP,
    bf16_t* __restrict__ Y, uint2* __restrict__ yaccA,
    uint2* __restrict__ yaccB, float* __restrict__ denP,
    const float* __restrict__ thrp, const float* __restrict__ leakp,
    const float* __restrict__ steepp)
{
  __shared__ bf16_t Ks[2][64 * 64];
  __shared__ bf16_t Vs[2][64 * 64];
  __shared__ __align__(16) u32 Ms[4][512];

  const int tid = threadIdx.x;
  const int w = tid >> 6, lane = tid & 63;
  const int r = lane & 15, g = lane >> 4;
  const int bid = blockIdx.x;
  const int bh  = (bid & 7) * 4 + ((bid >> 3) & 3);
  int u, c; item64_to_uc(bid >> 5, u, c);
  const int cmax = u >> 3;
  const bool diag = (c == cmax);
  const int nt = diag ? (u & 7) + 1 : 8;
  const int nch = cmax + 1;
  const int s = 4 * u + w;
  const int row0 = u * 64 + w * 16;
  const int qrow = row0 + r;
  const int hh = bh & (NH - 1), bb = bh >> 4;

  const bf16_t* Qh  = Q  + (size_t)bh * TT * DH;
  const bf16_t* Kh  = Km + (size_t)bh * TT * DH;
  const bf16_t* Vth = Vt + (size_t)bh * TT * DH;

  const float lk  = 1.0f / (1.0f + expf(-leakp[hh]));
  const float ilk = 1.0f - lk;
  const float st  = log1pf(expf(steepp[hh]));
  const float Lst = LOG2E * st;
  const float A0  = Lst * (fabsf(thrp[hh]) * 0.1f);

  float M = -1e30f, Z = 0.f;
  for (int c2 = 0; c2 < nch; ++c2) {
    const float2 mz = mzP[((size_t)(bh * 128 + s) * 4 + c2) * 16 + r];
    const float nm = fmaxf(M, mz.x);
    Z = Z * fexp2(M - nm) + mz.y * fexp2(mz.x - nm);
    M = nm;
  }
  const float rcpZ = frcp(Z);

  const float SCL = 0.125f * LOG2E;
  bf16x8 qf[2];
#pragma unroll
  for (int s2 = 0; s2 < 2; ++s2) {
    bf16x8 t = *reinterpret_cast<const bf16x8*>(Qh + (size_t)qrow * DH + s2 * 32 + g * 8);
#pragma unroll
    for (int i = 0; i < 8; ++i) t[i] = (bf16_t)((float)t[i] * SCL);
    qf[s2] = t;
  }
  bf16x8 ones;
#pragma unroll
  for (int i = 0; i < 8; ++i) ones[i] = (bf16_t)1.0f;

  uint2* MsU2 = reinterpret_cast<uint2*>(&Ms[w][0]);
  uint4* MsU4 = reinterpret_cast<uint4*>(&Ms[w][0]);

  auto STAGE = [&](int b, int t8) {
    const int kbase = c * 512 + t8 * 64;
#pragma unroll
    for (int it = 0; it < 2; ++it) {
      const int idx = it * 256 + tid;
      const int rr = idx >> 3, cc = idx & 7, gs = cc ^ (rr & 7);
      gload_lds16(Kh + (size_t)(kbase + rr) * DH + gs * 8, &Ks[b][idx * 8]);
      gload_lds16(Vth + (size_t)rr * TT + kbase + gs * 8, &Vs[b][idx * 8]);
    }
  };

  f32x4 yacc[4] = {};
  f32x4 dacc = {};

  STAGE(0, 0);
  for (int t8 = 0; t8 < nt; ++t8) {
    const int b = t8 & 1;
    asm volatile("s_waitcnt vmcnt(0)" ::: "memory");
    __syncthreads();
    if (t8 + 1 < nt) STAGE(b ^ 1, t8 + 1);
    const int kbase = c * 512 + t8 * 64;
    f32x4 sfT[4] = {};
#pragma unroll
    for (int s2 = 0; s2 < 2; ++s2) {
      bf16x8 kf[4];
#pragma unroll
      for (int ni = 0; ni < 4; ++ni)
        kf[ni] = *reinterpret_cast<const bf16x8*>(
            &Ks[b][(ni * 16 + r) * 64 + (((s2 << 2) | g) ^ (r & 7)) * 8]);
#pragma unroll
      for (int ni = 0; ni < 4; ++ni)
        sfT[ni] = __builtin_amdgcn_mfma_f32_16x16x32_bf16(kf[ni], qf[s2], sfT[ni], 0, 0, 0);
    }
    const bool dm = diag && (t8 == nt - 1);
#pragma unroll
    for (int ni = 0; ni < 4; ++ni) {
      float mv[4];
#pragma unroll
      for (int j = 0; j < 4; ++j) {
        float x = sfT[ni][j];
        if (dm) {
          const int kcol = kbase + ni * 16 + g * 4 + j;
          if (kcol > qrow) x = -1e30f;
        }
        const float p    = fexp2(x - M) * rcpZ;
        const float fire = frcp(1.0f + fexp2(A0 - Lst * p));
        mv[j] = p * fmaf(ilk, fire, lk);
      }
      MsU2[r * 16 + ((4 * ni + g) ^ ((r & 7) << 1))] =
          make_uint2(cvt_pk_bf16(mv[0], mv[1]), cvt_pk_bf16(mv[2], mv[3]));
    }
#pragma unroll
    for (int s2 = 0; s2 < 2; ++s2) {
      const uint4 aw = MsU4[r * 8 + ((s2 * 4 + g) ^ (r & 7))];
      const bf16x8 af = __builtin_bit_cast(bf16x8, aw);
      bf16x8 vf[4];
#pragma unroll
      for (int ni = 0; ni < 4; ++ni)
        vf[ni] = *reinterpret_cast<const bf16x8*>(
            &Vs[b][(ni * 16 + r) * 64 + (((s2 << 2) | g) ^ (r & 7)) * 8]);
#pragma unroll
      for (int ni = 0; ni < 4; ++ni)
        yacc[ni] = __builtin_amdgcn_mfma_f32_16x16x32_bf16(af, vf[ni], yacc[ni], 0, 0, 0);
      dacc = __builtin_amdgcn_mfma_f32_16x16x32_bf16(af, ones, dacc, 0, 0, 0);
    }
  }

  if (nch == 1) {
#pragma unroll
    for (int j = 0; j < 4; ++j) {
      const float rd = frcp(dacc[j] + 1e-8f);
      const int t = row0 + g * 4 + j;
#pragma unroll
      for (int ni = 0; ni < 4; ++ni)
        Y[((size_t)(bb * TT + t)) * C_ + hh * DH + ni * 16 + r] =
            (bf16_t)(yacc[ni][j] * rd);
    }
  } else {
    const int pid = bh * 288 + (sc_to_t(s, c) - 32);
    uint2* pb = (pid < 4096) ? (yaccA + (size_t)pid * 256)
                             : (yaccB + (size_t)(pid - 4096) * 256);
#pragma unroll
    for (int ni = 0; ni < 4; ++ni)
      pb[ni * 64 + lane] =
          make_uint2(cvt_pk_bf16(yacc[ni][0], yacc[ni][1]),
                     cvt_pk_bf16(yacc[ni][2], yacc[ni][3]));
    if (r == 0)
      *reinterpret_cast<float4*>(&denP[(size_t)pid * 16 + g * 4]) =
          make_float4(dacc[0], dacc[1], dacc[2], dacc[3]);
  }
}

// ---- P4: combine chunk partials for strips >= 32 ----------------------------
__global__ __launch_bounds__(256) void attn_p4(
    const uint2* __restrict__ yaccA, const uint2* __restrict__ yaccB,
    const float* __restrict__ denP, bf16_t* __restrict__ Y)
{
  const int bid = blockIdx.x;
  const int bh  = bid / 96;
  const int s   = 32 + (bid - bh * 96);
  const int nch = (s >> 5) + 1;
  const int hh = bh & (NH - 1), bb = bh >> 4;

  const int tid = threadIdx.x;
  const int w = tid >> 6, lane = tid & 63;
  const int r = lane & 15, g = lane >> 4;

  float acc[4] = {};
  float den[4] = {};
  for (int c = 0; c < nch; ++c) {
    const int pid = bh * 288 + (sc_to_t(s, c) - 32);
    const uint2* pb = (pid < 4096) ? (yaccA + (size_t)pid * 256)
                                   : (yaccB + (size_t)(pid - 4096) * 256);
    const uint2 u = pb[w * 64 + lane];
    acc[0] += __builtin_bit_cast(float, (u.x & 0xFFFFu) << 16);
    acc[1] += __builtin_bit_cast(float, (u.x & 0xFFFF0000u));
    acc[2] += __builtin_bit_cast(float, (u.y & 0xFFFFu) << 16);
    acc[3] += __builtin_bit_cast(float, (u.y & 0xFFFF0000u));
    const float4 d4 = *reinterpret_cast<const float4*>(&denP[(size_t)pid * 16 + g * 4]);
    den[0] += d4.x; den[1] += d4.y; den[2] += d4.z; den[3] += d4.w;
  }
#pragma unroll
  for (int j = 0; j < 4; ++j) {
    const float rd = 1.0f / (den[j] + 1e-8f);
    const int t = s * 16 + g * 4 + j;
    Y[((size_t)(bb * TT + t)) * C_ + hh * DH + w * 16 + r] = (bf16_t)(acc[j] * rd);
  }
}

// ---------------------------------------------------------------------------
extern "C" void kernel_launch(void* const* d_in, const int* in_sizes, int n_in,
                              void* d_out, int out_size, void* d_ws, size_t ws_size,
                              hipStream_t stream)
{
  const float* x      = (const float*)d_in[0];
  const float* ln1_w  = (const float*)d_in[1];
  const float* ln1_b  = (const float*)d_in[2];
  const float* w_attn = (const float*)d_in[3];
  const float* b_attn = (const float*)d_in[4];
  const float* w_proj = (const float*)d_in[5];
  const float* b_proj = (const float*)d_in[6];
  const float* thr    = (const float*)d_in[7];
  const float* leak   = (const float*)d_in[8];
  const float* steep  = (const float*)d_in[9];
  const float* ln2_w  = (const float*)d_in[10];
  const float* ln2_b  = (const float*)d_in[11];
  const float* w_fc   = (const float*)d_in[12];
  const float* b_fc   = (const float*)d_in[13];
  const float* w_mlp  = (const float*)d_in[14];
  const float* b_mlp  = (const float*)d_in[15];

  char* ws = (char*)d_ws;
  bf16_t* q    = (bf16_t*)(ws + 0);          //  8 MB
  bf16_t* k    = (bf16_t*)(ws + 8388608);    //  8 MB
  bf16_t* v    = (bf16_t*)(ws + 16777216);   //  8 MB (dead after p1t)
  bf16_t* vT   = (bf16_t*)(ws + 25165824);   //  8 MB
  bf16_t* gbuf = (bf16_t*)(ws + 0);          // 32 MB, aliases q/k/v/vT (dead)
  bf16_t* hbuf = (bf16_t*)(ws + 33554432);   //  8 MB, h -> Y -> h2
  float*  x2   = (float*) (ws + 41943040);   // 16 MB
  bf16_t* wT_attn = (bf16_t*)(ws + 58720256); // 6 MB
  bf16_t* wT_proj = (bf16_t*)(ws + 65011712); // 2 MB
  bf16_t* wT_fc   = (bf16_t*)(ws + 67108864); // 8 MB
  bf16_t* wT_mlp  = (bf16_t*)(ws + 75497472); // 8 MB -> 80 MB total

  // attention scratch (aliases v-slot and x2-slot, both dead during attention)
  uint2* yaccA = (uint2*)(ws + 16777216);
  uint2* yaccB = (uint2*)(ws + 41943040);
  float* denP  = (float*)(ws + 52428800);
  float2* mzP  = (float2*)(ws + 53477376);

  // proj split-K partial (dead q slot)
  bf16_t* pp1 = (bf16_t*)(ws + 0);
  // mlp_proj split-K partials (dead hbuf / wT_attn+wT_proj / wT_fc slots)
  bf16_t* mp1 = (bf16_t*)(ws + 33554432);
  bf16_t* mp2 = (bf16_t*)(ws + 58720256);
  bf16_t* mp3 = (bf16_t*)(ws + 67108864);

  float* out = (float*)d_out;

  // fused LN1 + 4 weight transposes (1 launch)
  prep<<<dim3(MROWS + 12288), dim3(256), 0, stream>>>(
      x, ln1_w, ln1_b, hbuf,
      w_attn, wT_attn, w_proj, wT_proj, w_fc, wT_fc, w_mlp, wT_mlp);

  // QKV: 128^2 tile, grid 768 = 3 blocks/CU fully resident
  gemm_sk<0><<<dim3(32, 24, 1), dim3(256), 0, stream>>>(
      hbuf, wT_attn, b_attn, nullptr, q, k, v, MROWS, 3072, 1024, 1024);

  // split-K attention; p1 carries the V transpose in blocks [0,4096)
  attn_p1t<<<dim3(4096 + 2560), dim3(256), 0, stream>>>(q, k, v, vT, mzP);
  attn_p3<<<dim3(2560), dim3(256), 0, stream>>>(
      q, k, vT, mzP, hbuf, yaccA, yaccB, denP, thr, leak, steep);
  attn_p4<<<dim3(3072), dim3(256), 0, stream>>>(yaccA, yaccB, denP, hbuf);

  // attn projection, split-K 2: z0 -> raw fp32 in x2, z1 -> bf16 pp1
  gemm_sk<3><<<dim3(32, 8, 2), dim3(256), 0, stream>>>(
      hbuf, wT_proj, nullptr, x2, pp1, nullptr, nullptr, MROWS, 1024, 512, 1024);

  // LN2 fused with proj combine
  ln2_fuse<<<dim3(MROWS), dim3(256), 0, stream>>>(
      x2, pp1, x, b_proj, ln2_w, ln2_b, x2, hbuf);

  // MLP fc + GELU: 256x128 pipeline with 2-D XCD rectangles
  gemmP<<<dim3(512, 1, 1), dim3(512), 0, stream>>>(
      hbuf, wT_fc, b_fc, gbuf, 4096, 1024);

  // MLP proj, split-K 4: z0 -> raw fp32 in out, z1-3 -> bf16 mp1..3
  gemm_sk<3><<<dim3(32, 8, 4), dim3(256), 0, stream>>>(
      gbuf, wT_mlp, nullptr, out, mp1, mp2, mp3, MROWS, 1024, 1024, 4096);

  // final combine: out += mp1+mp2+mp3 + b_mlp + x2
  combine3<<<dim3(4096), dim3(256), 0, stream>>>(out, mp1, mp2, mp3, b_mlp, x2);
}